// Round 1
// baseline (3987.660 us; speedup 1.0000x reference)
//
#include <hip/hip_runtime.h>
#include <math.h>
#include <stdint.h>

#define NBV 65536
#define EV  1048576
#define BV  128
#define K1V 410
#define K2V 205
#define K3V 103
#define NEG_BIG (-1.0e38f)

__device__ __forceinline__ float lrelu(float x){ return x > 0.f ? x : 0.2f*x; }

// async global->LDS 16B copy: LDS dest is wave-uniform base + lane*16,
// global src is per-lane. vmcnt-tracked; drained by the compiler's
// s_waitcnt before s_barrier.
typedef __attribute__((address_space(3))) unsigned int lds_u32;
typedef __attribute__((address_space(1))) unsigned int glb_u32;
__device__ __forceinline__ void lds_load16(const float* g, float* l){
  __builtin_amdgcn_global_load_lds((const glb_u32*)(uintptr_t)g,
                                   (lds_u32*)(uintptr_t)l, 16, 0, 0);
}

// ---------------- diagnostics sentinel ----------------
__global__ void k_sentinel(float* out, float v){
  int i = threadIdx.x;
  if (i < 128) out[i] = v;
}

// ---------------- utility ----------------
__global__ void k_fill1(float* p, int n){
  int i = blockIdx.x*blockDim.x + threadIdx.x;
  if (i < n) p[i] = 1.f;
}

__global__ void k_zero_i(int* p, int n){
  int i = blockIdx.x*blockDim.x + threadIdx.x;
  if (i < n) p[i] = 0;
}

// ---------------- CSR build (int atomics only) ----------------
__global__ void k_hist(const int* dst, int* dcnt){
  int e = blockIdx.x*blockDim.x + threadIdx.x;
  if (e < EV) atomicAdd(&dcnt[dst[e]], 1);
}

__global__ void k_scan1(const int* dcnt, int* rp, int* bsum){
  __shared__ int sc[256];
  int t = threadIdx.x, i = blockIdx.x*256 + t;
  int v = dcnt[i];
  sc[t] = v; __syncthreads();
  for (int o = 1; o < 256; o <<= 1){
    int x = (t >= o) ? sc[t-o] : 0;
    __syncthreads();
    sc[t] += x;
    __syncthreads();
  }
  rp[i] = sc[t];
  if (t == 255) bsum[blockIdx.x] = sc[t];
}

__global__ void k_scan2(int* bsum){
  __shared__ int sc[256];
  int t = threadIdx.x;
  int v = bsum[t];
  sc[t] = v; __syncthreads();
  for (int o = 1; o < 256; o <<= 1){
    int x = (t >= o) ? sc[t-o] : 0;
    __syncthreads();
    sc[t] += x;
    __syncthreads();
  }
  bsum[t] = sc[t] - v;
}

__global__ void k_scan3(int* rp, const int* dcnt, const int* bsum){
  int t = threadIdx.x, i = blockIdx.x*256 + t;
  rp[i] = rp[i] - dcnt[i] + bsum[blockIdx.x];
  if (i == 0) rp[NBV] = EV;
}

__global__ void k_scatter(const int* src, const int* dst, const int* rp, int* fill,
                          int* csr_src, int* csr_eid){
  int e = blockIdx.x*blockDim.x + threadIdx.x;
  if (e < EV){
    int d = dst[e];
    int pos = atomicAdd(&fill[d], 1);
    int slot = rp[d] + pos;
    csr_src[slot] = src[e];
    csr_eid[slot] = e;
  }
}

// ---------------- small precomputes ----------------
__global__ void k_invnorm(const float* wv, float* outv){
  __shared__ float sc[128];
  int t = threadIdx.x;
  float v = wv[t];
  sc[t] = v*v; __syncthreads();
  for (int o = 64; o > 0; o >>= 1){ if (t < o) sc[t] += sc[t+o]; __syncthreads(); }
  if (t == 0) outv[0] = 1.f / sqrtf(sc[0]);
}

__global__ void k_ve(const float* g_we, const float* g_ae, float* ve){
  int t = threadIdx.x;
  if (t < 28){
    int ed = t >> 2, h = t & 3;
    float a = 0.f;
    for (int c = 0; c < 32; c++) a += g_we[ed*128 + h*32 + c] * g_ae[h*32 + c];
    ve[t] = a;
  }
}

__global__ void k_ale(const float* ea, const float* ve, float* ALE){
  int e = blockIdx.x*blockDim.x + threadIdx.x;
  if (e < EV){
    float a0=0.f,a1=0.f,a2=0.f,a3=0.f;
    for (int ed = 0; ed < 7; ed++){
      float x = ea[e*7 + ed];
      a0 += x*ve[ed*4+0]; a1 += x*ve[ed*4+1]; a2 += x*ve[ed*4+2]; a3 += x*ve[ed*4+3];
    }
    float4 o; o.x=a0; o.y=a1; o.z=a2; o.w=a3;
    *(float4*)&ALE[(size_t)e*4] = o;
  }
}

// ---------------- SAGE mean aggregation (XCD-swizzled, 4-deep gather) ----------------
__global__ void __launch_bounds__(256) k_sage_agg(const float* X, const float* nmask,
    const int* rp, const int* csr_src, float* AGG, int masked){
  int g = blockIdx.x & 127;
  int blk = blockIdx.x >> 7;
  int i = g*512 + blk*8 + (threadIdx.x >> 5);
  int c4 = threadIdx.x & 31;
  float ax=0.f,ay=0.f,az=0.f,aw=0.f,cnt=0.f;
  if (!masked || nmask[i] > 0.f){
    int r0 = rp[i], r1 = rp[i+1];
    int s = r0;
    for (; s + 4 <= r1; s += 4){
      int sn0 = csr_src[s+0], sn1 = csr_src[s+1], sn2 = csr_src[s+2], sn3 = csr_src[s+3];
      float4 v0 = *(const float4*)&X[((size_t)sn0 << 7) + (c4 << 2)];
      float4 v1 = *(const float4*)&X[((size_t)sn1 << 7) + (c4 << 2)];
      float4 v2 = *(const float4*)&X[((size_t)sn2 << 7) + (c4 << 2)];
      float4 v3 = *(const float4*)&X[((size_t)sn3 << 7) + (c4 << 2)];
      float nm0 = masked ? nmask[sn0] : 1.f;
      float nm1 = masked ? nmask[sn1] : 1.f;
      float nm2 = masked ? nmask[sn2] : 1.f;
      float nm3 = masked ? nmask[sn3] : 1.f;
      if (nm0 > 0.f){ ax += v0.x; ay += v0.y; az += v0.z; aw += v0.w; cnt += 1.f; }
      if (nm1 > 0.f){ ax += v1.x; ay += v1.y; az += v1.z; aw += v1.w; cnt += 1.f; }
      if (nm2 > 0.f){ ax += v2.x; ay += v2.y; az += v2.z; aw += v2.w; cnt += 1.f; }
      if (nm3 > 0.f){ ax += v3.x; ay += v3.y; az += v3.z; aw += v3.w; cnt += 1.f; }
    }
    for (; s < r1; s++){
      int sn = csr_src[s];
      float nm = masked ? nmask[sn] : 1.f;
      if (nm > 0.f){
        const float4 v = *(const float4*)&X[((size_t)sn << 7) + (c4 << 2)];
        ax += v.x; ay += v.y; az += v.z; aw += v.w; cnt += 1.f;
      }
    }
  }
  float inv = 1.f / fmaxf(cnt, 1.f);
  float4 o; o.x = ax*inv; o.y = ay*inv; o.z = az*inv; o.w = aw*inv;
  *(float4*)&AGG[((size_t)i << 7) + (c4 << 2)] = o;
}

// ---------------- dual GEMM f32, K-chunk streamed, double-buffered ----------------
// r12 theory: 74KB LDS (full W resident) capped residency at 2 blocks/CU and the
// 34-barrier loop exposed every drain (VALUBusy 58%). Now BOTH operands stream in
// K=16 chunks (LDS 34KB -> 4 blocks/CU), ONE barrier per chunk, W staged by async
// global_load_lds (wave-uniform dest = 2 contiguous rows/wave), A prefetch issued
// before compute and ds_written after (write-late). launch_bounds(512,8) pins
// VGPR<=64 (the 64/128 occupancy cliff).
__global__ void __launch_bounds__(512, 8) k_gemm(const float* A1, const float* A2,
    const float* W1, const float* W2, const float* bias,
    float* OUT, int has2, int relu, int hasb){
  __shared__ float ws[2][16][128];   // linear: global_load_lds dest (no pad!)
  __shared__ float as[2][16][140];   // transposed A chunk; 140 -> 2-way banks on write
  int t = threadIdx.x;
  int n0 = blockIdx.x * 128;
  int rowg = t >> 5;
  int colg = t & 31;
  int rb = rowg * 8;
  int jb = colg * 4;
  int an = t >> 2;              // A-stage row 0..127
  int ak = (t & 3) << 2;        // A-stage k offset {0,4,8,12}
  int wvid = t >> 6;            // wave 0..7 -> ws rows 2w,2w+1
  int ln = t & 63;
  float acc[8][4];
  #pragma unroll
  for (int r = 0; r < 8; r++)
    #pragma unroll
    for (int j = 0; j < 4; j++) acc[r][j] = 0.f;
  int nmat = has2 ? 2 : 1;
  for (int m = 0; m < nmat; m++){
    const float* A = (m == 0) ? A1 : A2;
    const float* W = (m == 0) ? W1 : W2;
    const float* Arow  = A + (((size_t)(n0 + an)) << 7) + ak;
    const float* Wlane = W + wvid*256 + ln*4;
    // stage chunk 0 (previous matrix's readers are past the c=7 barrier)
    float4 rA = *(const float4*)Arow;
    lds_load16(Wlane, &ws[0][wvid*2][0]);
    as[0][ak+0][an] = rA.x;
    as[0][ak+1][an] = rA.y;
    as[0][ak+2][an] = rA.z;
    as[0][ak+3][an] = rA.w;
    __syncthreads();   // drains vmcnt (ws chunk0) + lgkm (as chunk0)
    #pragma unroll 2
    for (int c = 0; c < 8; c++){
      int cur = c & 1, nxt = cur ^ 1;
      if (c < 7){
        rA = *(const float4*)(Arow + (c+1)*16);            // issue early
        lds_load16(Wlane + (c+1)*2048, &ws[nxt][wvid*2][0]); // async, lands by barrier
      }
      #pragma unroll
      for (int kk = 0; kk < 16; kk++){
        float4 w4 = *(const float4*)&ws[cur][kk][jb];
        float4 aL = *(const float4*)&as[cur][kk][rb];
        float4 aH = *(const float4*)&as[cur][kk][rb+4];
        float a0=aL.x,a1=aL.y,a2=aL.z,a3=aL.w,a4=aH.x,a5=aH.y,a6=aH.z,a7=aH.w;
        acc[0][0]+=a0*w4.x; acc[0][1]+=a0*w4.y; acc[0][2]+=a0*w4.z; acc[0][3]+=a0*w4.w;
        acc[1][0]+=a1*w4.x; acc[1][1]+=a1*w4.y; acc[1][2]+=a1*w4.z; acc[1][3]+=a1*w4.w;
        acc[2][0]+=a2*w4.x; acc[2][1]+=a2*w4.y; acc[2][2]+=a2*w4.z; acc[2][3]+=a2*w4.w;
        acc[3][0]+=a3*w4.x; acc[3][1]+=a3*w4.y; acc[3][2]+=a3*w4.z; acc[3][3]+=a3*w4.w;
        acc[4][0]+=a4*w4.x; acc[4][1]+=a4*w4.y; acc[4][2]+=a4*w4.z; acc[4][3]+=a4*w4.w;
        acc[5][0]+=a5*w4.x; acc[5][1]+=a5*w4.y; acc[5][2]+=a5*w4.z; acc[5][3]+=a5*w4.w;
        acc[6][0]+=a6*w4.x; acc[6][1]+=a6*w4.y; acc[6][2]+=a6*w4.z; acc[6][3]+=a6*w4.w;
        acc[7][0]+=a7*w4.x; acc[7][1]+=a7*w4.y; acc[7][2]+=a7*w4.z; acc[7][3]+=a7*w4.w;
      }
      if (c < 7){                    // write-late: HBM/L2 latency hid under compute
        as[nxt][ak+0][an] = rA.x;
        as[nxt][ak+1][an] = rA.y;
        as[nxt][ak+2][an] = rA.z;
        as[nxt][ak+3][an] = rA.w;
      }
      __syncthreads();               // single barrier per chunk
    }
  }
  float bj0=0.f,bj1=0.f,bj2=0.f,bj3=0.f;
  if (hasb){
    bj0 = bias[jb+0]; bj1 = bias[jb+1]; bj2 = bias[jb+2]; bj3 = bias[jb+3];
  }
  for (int r = 0; r < 8; r++){
    float4 o;
    o.x = acc[r][0]+bj0; o.y = acc[r][1]+bj1; o.z = acc[r][2]+bj2; o.w = acc[r][3]+bj3;
    if (relu){
      o.x = fmaxf(o.x,0.f); o.y = fmaxf(o.y,0.f); o.z = fmaxf(o.z,0.f); o.w = fmaxf(o.w,0.f);
    }
    *(float4*)&OUT[((size_t)(n0+rb+r) << 7) + jb] = o;
  }
}

// ---------------- scores (32 lanes/node, shfl reduce) ----------------
__global__ void __launch_bounds__(256) k_score1(const float* X, const float* pw, const float* invn, float* s){
  int gid = blockIdx.x*256 + threadIdx.x;
  int i = gid >> 5, c4 = gid & 31;
  float4 v = *(const float4*)&X[((size_t)i << 7) + (c4 << 2)];
  float4 wv = *(const float4*)&pw[c4 << 2];
  float a = v.x*wv.x + v.y*wv.y + v.z*wv.z + v.w*wv.w;
  for (int o = 16; o > 0; o >>= 1) a += __shfl_down(a, o, 32);
  if (c4 == 0) s[i] = tanhf(a * invn[0]);
}

__global__ void __launch_bounds__(256) k_qr(const float* X, const float* wrel, const float* wroot,
                                            float* q, float* r){
  int gid = blockIdx.x*256 + threadIdx.x;
  int i = gid >> 5, c4 = gid & 31;
  float4 v = *(const float4*)&X[((size_t)i << 7) + (c4 << 2)];
  float4 wa = *(const float4*)&wrel[c4 << 2];
  float4 wb = *(const float4*)&wroot[c4 << 2];
  float aq = v.x*wa.x + v.y*wa.y + v.z*wa.z + v.w*wa.w;
  float ar = v.x*wb.x + v.y*wb.y + v.z*wb.z + v.w*wb.w;
  for (int o = 16; o > 0; o >>= 1){
    aq += __shfl_down(aq, o, 32);
    ar += __shfl_down(ar, o, 32);
  }
  if (c4 == 0){ q[i] = aq; r[i] = ar; }
}

__global__ void k_gconv(const float* q, const float* r, const float* nmask,
    const int* rp, const int* csr_src, const float* brel, float* s){
  int i = blockIdx.x*blockDim.x + threadIdx.x;
  if (i >= NBV) return;
  float acc = 0.f;
  if (nmask[i] > 0.f){
    int r0 = rp[i], r1 = rp[i+1];
    int t2 = r0;
    for (; t2 + 4 <= r1; t2 += 4){
      int sn0 = csr_src[t2+0], sn1 = csr_src[t2+1], sn2 = csr_src[t2+2], sn3 = csr_src[t2+3];
      float nm0 = nmask[sn0], nm1 = nmask[sn1], nm2 = nmask[sn2], nm3 = nmask[sn3];
      float q0 = q[sn0], q1 = q[sn1], q2 = q[sn2], q3 = q[sn3];
      if (nm0 > 0.f) acc += q0;
      if (nm1 > 0.f) acc += q1;
      if (nm2 > 0.f) acc += q2;
      if (nm3 > 0.f) acc += q3;
    }
    for (; t2 < r1; t2++){
      int sn = csr_src[t2];
      if (nmask[sn] > 0.f) acc += q[sn];
    }
  }
  s[i] = tanhf(acc + brel[0] + r[i]);
}

// ---------------- top-k pool (stable tie-break == jax.lax.top_k) ----------------
__global__ void __launch_bounds__(512) k_pool(const float* s, float* nmask, float* sel, int K){
  __shared__ float sc[512];
  int b = blockIdx.x, t = threadIdx.x;
  int i = b*512 + t;
  float nm = nmask[i];
  float sv = s[i];
  float ms = (nm > 0.f) ? sv : NEG_BIG;
  sc[t] = ms;
  __syncthreads();
  int rank = 0;
  for (int j = 0; j < 512; j++){
    float o = sc[j];
    rank += ((o > ms) || (o == ms && j < t)) ? 1 : 0;
  }
  bool selb = rank < K;
  nmask[i] = selb ? 1.f : 0.f;
  sel[i] = selb ? sv : 0.f;
}

// scale kept rows by score (in place) + gap partials — no atomics.
__global__ void __launch_bounds__(128) k_scale_part(float* X, const float* sel, float* part){
  int b = blockIdx.x >> 3, q = blockIdx.x & 7, c = threadIdx.x;
  float acc = 0.f;
  for (int n = q*64; n < q*64 + 64; n++){
    int i = b*512 + n;
    float v = X[((size_t)i << 7) + c] * sel[i];
    X[((size_t)i << 7) + c] = v;
    acc += v;
  }
  part[(size_t)blockIdx.x*128 + c] = acc;
}

__global__ void __launch_bounds__(128) k_gap_final(const float* part, float* gap, float invK){
  int b = blockIdx.x, c = threadIdx.x;
  float s = 0.f;
  for (int q = 0; q < 8; q++) s += part[(size_t)(b*8+q)*128 + c];
  gap[b*128 + c] = s * invK;
}

// ---------------- GAT pieces ----------------
__global__ void k_heads(const float* xs, const float* a_s, const float* a_d,
                        float* alS, float* alD){
  int gid = blockIdx.x*blockDim.x + threadIdx.x;
  int i = gid >> 2, h = gid & 3;
  if (i >= NBV) return;
  const float4* xr = (const float4*)&xs[((size_t)i << 7) + h*32];
  const float4* wa = (const float4*)&a_s[h*32];
  const float4* wd = (const float4*)&a_d[h*32];
  float as_ = 0.f, ad_ = 0.f;
  for (int c4 = 0; c4 < 8; c4++){
    float4 v = xr[c4]; float4 A = wa[c4]; float4 D = wd[c4];
    as_ += v.x*A.x + v.y*A.y + v.z*A.z + v.w*A.w;
    ad_ += v.x*D.x + v.y*D.y + v.z*D.z + v.w*D.w;
  }
  alS[gid] = as_; alD[gid] = ad_;
}

// edge-attr masked mean: per-block partials (no atomics)
__global__ void __launch_bounds__(256) k_ea_part(const float* ea, const int* srcA, const int* dstA,
    const float* nmask, float* part){
  float p[8] = {0.f,0.f,0.f,0.f,0.f,0.f,0.f,0.f};
  for (int e = blockIdx.x*256 + threadIdx.x; e < EV; e += 256*256){
    if (nmask[srcA[e]] > 0.f && nmask[dstA[e]] > 0.f){
      for (int d = 0; d < 7; d++) p[d] += ea[e*7 + d];
      p[7] += 1.f;
    }
  }
  __shared__ float red[256];
  for (int comp = 0; comp < 8; comp++){
    red[threadIdx.x] = p[comp]; __syncthreads();
    for (int o = 128; o > 0; o >>= 1){ if (threadIdx.x < o) red[threadIdx.x] += red[threadIdx.x + o]; __syncthreads(); }
    if (threadIdx.x == 0) part[blockIdx.x*8 + comp] = red[0];
    __syncthreads();
  }
}

__global__ void k_ea_final(const float* part, float* easum){
  int h = threadIdx.x;
  if (h < 8){
    float s = 0.f;
    for (int b = 0; b < 256; b++) s += part[b*8 + h];
    easum[h] = s;
  }
}

__global__ void k_alse(const float* easum, const float* ve, float* alse){
  if (threadIdx.x == 0 && blockIdx.x == 0){
    float cnt = fmaxf(easum[7], 1.f);
    for (int h = 0; h < 4; h++){
      float s = 0.f;
      for (int ed = 0; ed < 7; ed++) s += (easum[ed]/cnt) * ve[ed*4 + h];
      alse[h] = s;
    }
  }
}

// GAT: 32 threads/node, XCD-swizzled, 4-deep gathers + in-order online softmax.
__global__ void __launch_bounds__(256) k_gat(const float* xs, const float* alS, const float* alD,
    const float* ALE, const float* nmask, const int* rp, const int* csr_src,
    const int* csr_eid, const float* alse, const float* g_b, float* OUT){
  int g = blockIdx.x & 127;
  int blk = blockIdx.x >> 7;
  int i = g*512 + blk*8 + (threadIdx.x >> 5);
  int lane = threadIdx.x & 31;
  int h = lane >> 3;
  int cidx = h*8 + (lane & 7);
  float nmi = nmask[i];
  const float4* xs4 = (const float4*)xs;
  float m = 0.f, den = 0.f;
  float4 acc; acc.x=0.f; acc.y=0.f; acc.z=0.f; acc.w=0.f;
  if (nmi > 0.f){
    float ald_i = alD[i*4 + h];
    m = lrelu(alS[i*4 + h] + ald_i + alse[h]);   // aself
    den = 1.f;
    acc = xs4[(size_t)i*32 + cidx];
    int r0 = rp[i], r1 = rp[i+1];
    int s = r0;
    for (; s + 4 <= r1; s += 4){
      int sn0 = csr_src[s+0], sn1 = csr_src[s+1], sn2 = csr_src[s+2], sn3 = csr_src[s+3];
      int e0 = csr_eid[s+0], e1 = csr_eid[s+1], e2 = csr_eid[s+2], e3 = csr_eid[s+3];
      float nm0 = nmask[sn0], nm1 = nmask[sn1], nm2 = nmask[sn2], nm3 = nmask[sn3];
      float al0 = alS[sn0*4 + h], al1 = alS[sn1*4 + h], al2 = alS[sn2*4 + h], al3 = alS[sn3*4 + h];
      float ae0 = ALE[(size_t)e0*4 + h], ae1 = ALE[(size_t)e1*4 + h];
      float ae2 = ALE[(size_t)e2*4 + h], ae3 = ALE[(size_t)e3*4 + h];
      float4 v0 = xs4[(size_t)sn0*32 + cidx];
      float4 v1 = xs4[(size_t)sn1*32 + cidx];
      float4 v2 = xs4[(size_t)sn2*32 + cidx];
      float4 v3 = xs4[(size_t)sn3*32 + cidx];
      if (nm0 > 0.f){
        float a = lrelu(al0 + ald_i + ae0);
        float mn = fmaxf(m, a); float pm = expf(m - mn); float pa = expf(a - mn);
        den = den*pm + pa;
        acc.x = acc.x*pm + pa*v0.x; acc.y = acc.y*pm + pa*v0.y;
        acc.z = acc.z*pm + pa*v0.z; acc.w = acc.w*pm + pa*v0.w;
        m = mn;
      }
      if (nm1 > 0.f){
        float a = lrelu(al1 + ald_i + ae1);
        float mn = fmaxf(m, a); float pm = expf(m - mn); float pa = expf(a - mn);
        den = den*pm + pa;
        acc.x = acc.x*pm + pa*v1.x; acc.y = acc.y*pm + pa*v1.y;
        acc.z = acc.z*pm + pa*v1.z; acc.w = acc.w*pm + pa*v1.w;
        m = mn;
      }
      if (nm2 > 0.f){
        float a = lrelu(al2 + ald_i + ae2);
        float mn = fmaxf(m, a); float pm = expf(m - mn); float pa = expf(a - mn);
        den = den*pm + pa;
        acc.x = acc.x*pm + pa*v2.x; acc.y = acc.y*pm + pa*v2.y;
        acc.z = acc.z*pm + pa*v2.z; acc.w = acc.w*pm + pa*v2.w;
        m = mn;
      }
      if (nm3 > 0.f){
        float a = lrelu(al3 + ald_i + ae3);
        float mn = fmaxf(m, a); float pm = expf(m - mn); float pa = expf(a - mn);
        den = den*pm + pa;
        acc.x = acc.x*pm + pa*v3.x; acc.y = acc.y*pm + pa*v3.y;
        acc.z = acc.z*pm + pa*v3.z; acc.w = acc.w*pm + pa*v3.w;
        m = mn;
      }
    }
    for (; s < r1; s++){
      int sn = csr_src[s];
      if (nmask[sn] > 0.f){
        float a = lrelu(alS[sn*4 + h] + ald_i + ALE[(size_t)csr_eid[s]*4 + h]);
        float4 v = xs4[(size_t)sn*32 + cidx];
        float mn = fmaxf(m, a); float pm = expf(m - mn); float pa = expf(a - mn);
        den = den*pm + pa;
        acc.x = acc.x*pm + pa*v.x; acc.y = acc.y*pm + pa*v.y;
        acc.z = acc.z*pm + pa*v.z; acc.w = acc.w*pm + pa*v.w;
        m = mn;
      }
    }
  }
  den = fmaxf(den, 1e-16f);
  float rd = 1.f/den;
  int cb = cidx << 2;
  float4 o;
  o.x = fmaxf(acc.x*rd + g_b[cb+0], 0.f);
  o.y = fmaxf(acc.y*rd + g_b[cb+1], 0.f);
  o.z = fmaxf(acc.z*rd + g_b[cb+2], 0.f);
  o.w = fmaxf(acc.w*rd + g_b[cb+3], 0.f);
  *(float4*)&OUT[((size_t)i << 7) + cb] = o;
}

// ---------------- final MLP ----------------
__global__ void __launch_bounds__(128) k_mlp(const float* x1g, const float* x2g, const float* x3g,
    const float* l1w, const float* l1b, const float* l2w, const float* l2b,
    const float* l3w, const float* l3b, float* out){
  __shared__ float hh[128];
  __shared__ float h2[128];
  __shared__ float h3[64];
  int b = blockIdx.x, t = threadIdx.x;
  hh[t] = x1g[b*128 + t] + x2g[b*128 + t] + x3g[b*128 + t];
  __syncthreads();
  float a = l1b[t];
  for (int k = 0; k < 128; k++) a += hh[k] * l1w[k*128 + t];
  h2[t] = fmaxf(a, 0.f);
  __syncthreads();
  if (t < 64){
    float a2 = l2b[t];
    for (int k = 0; k < 128; k++) a2 += h2[k] * l2w[k*64 + t];
    h3[t] = fmaxf(a2, 0.f);
  }
  __syncthreads();
  if (t == 0){
    float z = l3b[0];
    for (int k = 0; k < 64; k++) z += h3[k] * l3w[k];
    out[b] = 1.f/(1.f + expf(-z));
  }
}

// ---------------- launch ----------------
extern "C" void kernel_launch(void* const* d_in, const int* in_sizes, int n_in,
                              void* d_out, int out_size, void* d_ws, size_t ws_size,
                              hipStream_t stream){
  const float* x       = (const float*)d_in[0];
  const int*   ei      = (const int*)d_in[1];
  const float* ea      = (const float*)d_in[2];
  const float* c1_wl   = (const float*)d_in[3];
  const float* c1_bl   = (const float*)d_in[4];
  const float* c1_wr   = (const float*)d_in[5];
  const float* p1_w    = (const float*)d_in[6];
  const float* c2_wl   = (const float*)d_in[7];
  const float* c2_bl   = (const float*)d_in[8];
  const float* c2_wr   = (const float*)d_in[9];
  const float* p2_wrel = (const float*)d_in[10];
  const float* p2_brel = (const float*)d_in[11];
  const float* p2_wroot= (const float*)d_in[12];
  const float* g_w     = (const float*)d_in[13];
  const float* g_as    = (const float*)d_in[14];
  const float* g_ad    = (const float*)d_in[15];
  const float* g_we    = (const float*)d_in[16];
  const float* g_ae    = (const float*)d_in[17];
  const float* g_b     = (const float*)d_in[18];
  const float* p3_wrel = (const float*)d_in[19];
  const float* p3_brel = (const float*)d_in[20];
  const float* p3_wroot= (const float*)d_in[21];
  const float* l1_w    = (const float*)d_in[22];
  const float* l1_b    = (const float*)d_in[23];
  const float* l2_w    = (const float*)d_in[24];
  const float* l2_b    = (const float*)d_in[25];
  const float* l3_w    = (const float*)d_in[26];
  const float* l3_b    = (const float*)d_in[27];
  float* out = (float*)d_out;
  (void)in_sizes; (void)n_in; (void)out_size;

  // Workspace layout (f32, ~137 MB)
  char* w = (char*)d_ws;
  size_t off = 0;
  float* AGG  = (float*)(w + off); off += (size_t)NBV*128*4;
  float* F1   = (float*)(w + off); off += (size_t)NBV*128*4;
  float* F2   = (float*)(w + off); off += (size_t)NBV*128*4;
  float* ALE  = (float*)(w + off); off += (size_t)EV*4*4;
  float* sA   = (float*)(w + off); off += (size_t)NBV*4;
  float* sel  = (float*)(w + off); off += (size_t)NBV*4;
  float* qv   = (float*)(w + off); off += (size_t)NBV*4;
  float* rv   = (float*)(w + off); off += (size_t)NBV*4;
  float* nmask= (float*)(w + off); off += (size_t)NBV*4;
  float* alS  = (float*)(w + off); off += (size_t)NBV*4*4;
  float* alD  = (float*)(w + off); off += (size_t)NBV*4*4;
  float* x1g  = (float*)(w + off); off += (size_t)BV*128*4;
  float* x2g  = (float*)(w + off); off += (size_t)BV*128*4;
  float* x3g  = (float*)(w + off); off += (size_t)BV*128*4;
  float* sml  = (float*)(w + off); off += 64*4;      // [0]=invnorm [8..15]=easum [16..19]=alse [20..47]=ve
  float* eprt = (float*)(w + off); off += 2048*4;
  float* gprt = (float*)(w + off); off += (size_t)1024*128*4;
  int* csr_src = (int*)(w + off); off += (size_t)EV*4;
  int* csr_eid = (int*)(w + off); off += (size_t)EV*4;
  int* rp      = (int*)(w + off); off += (size_t)(NBV+64)*4;
  int* dcnt    = (int*)(w + off); off += (size_t)(NBV+64)*4;
  int* bsum    = (int*)(w + off); off += 1024;
  size_t needed = off;

  float sentinel = (ws_size >= needed) ? 0.125f : 0.875f;
  k_sentinel<<<1, 128, 0, stream>>>(out, sentinel);

  const int* srcA = ei;
  const int* dstA = ei + EV;

  // ---- setup ----
  k_fill1<<<NBV/256, 256, 0, stream>>>(nmask, NBV);
  k_zero_i<<<(NBV+256)/256, 256, 0, stream>>>(dcnt, NBV+1);
  k_hist<<<EV/256, 256, 0, stream>>>(dstA, dcnt);
  k_scan1<<<256, 256, 0, stream>>>(dcnt, rp, bsum);
  k_scan2<<<1, 256, 0, stream>>>(bsum);
  k_scan3<<<256, 256, 0, stream>>>(rp, dcnt, bsum);
  k_zero_i<<<(NBV+256)/256, 256, 0, stream>>>(dcnt, NBV+1);
  k_scatter<<<EV/256, 256, 0, stream>>>(srcA, dstA, rp, dcnt, csr_src, csr_eid);
  k_ve<<<1, 32, 0, stream>>>(g_we, g_ae, sml+20);
  k_ale<<<EV/256, 256, 0, stream>>>(ea, sml+20, ALE);

  // ---- block 1: SAGE -> TopK(410) -> gap  (x -> F1) ----
  k_invnorm<<<1, 128, 0, stream>>>(p1_w, sml);
  k_sage_agg<<<(NBV*32)/256, 256, 0, stream>>>(x, nmask, rp, csr_src, AGG, 0);
  k_gemm<<<NBV/128, 512, 0, stream>>>(AGG, x, c1_wl, c1_wr, c1_bl, F1, 1, 1, 1);
  k_score1<<<(NBV*32)/256, 256, 0, stream>>>(F1, p1_w, sml, sA);
  k_pool<<<BV, 512, 0, stream>>>(sA, nmask, sel, K1V);
  k_scale_part<<<BV*8, 128, 0, stream>>>(F1, sel, gprt);
  k_gap_final<<<BV, 128, 0, stream>>>(gprt, x1g, 1.f/(float)K1V);

  // ---- block 2: SAGE -> SAGPool(205) -> gap  (F1 -> F2) ----
  k_sage_agg<<<(NBV*32)/256, 256, 0, stream>>>(F1, nmask, rp, csr_src, AGG, 1);
  k_gemm<<<NBV/128, 512, 0, stream>>>(AGG, F1, c2_wl, c2_wr, c2_bl, F2, 1, 1, 1);
  k_qr<<<(NBV*32)/256, 256, 0, stream>>>(F2, p2_wrel, p2_wroot, qv, rv);
  k_gconv<<<NBV/256, 256, 0, stream>>>(qv, rv, nmask, rp, csr_src, p2_brel, sA);
  k_pool<<<BV, 512, 0, stream>>>(sA, nmask, sel, K2V);
  k_scale_part<<<BV*8, 128, 0, stream>>>(F2, sel, gprt);
  k_gap_final<<<BV, 128, 0, stream>>>(gprt, x2g, 1.f/(float)K2V);

  // ---- block 3: GAT -> SAGPool(103) -> gap  (F2 -> xs=AGG -> F1) ----
  k_gemm<<<NBV/128, 512, 0, stream>>>(F2, F2, g_w, g_w, g_b, AGG, 0, 0, 0);  // xs = F2 @ g_w
  k_heads<<<(NBV*4)/256, 256, 0, stream>>>(AGG, g_as, g_ad, alS, alD);
  k_ea_part<<<256, 256, 0, stream>>>(ea, srcA, dstA, nmask, eprt);
  k_ea_final<<<1, 64, 0, stream>>>(eprt, sml+8);
  k_alse<<<1, 64, 0, stream>>>(sml+8, sml+20, sml+16);
  k_gat<<<(NBV*32)/256, 256, 0, stream>>>(AGG, alS, alD, ALE, nmask, rp, csr_src, csr_eid, sml+16, g_b, F1);
  k_qr<<<(NBV*32)/256, 256, 0, stream>>>(F1, p3_wrel, p3_wroot, qv, rv);
  k_gconv<<<NBV/256, 256, 0, stream>>>(qv, rv, nmask, rp, csr_src, p3_brel, sA);
  k_pool<<<BV, 512, 0, stream>>>(sA, nmask, sel, K3V);
  k_scale_part<<<BV*8, 128, 0, stream>>>(F1, sel, gprt);
  k_gap_final<<<BV, 128, 0, stream>>>(gprt, x3g, 1.f/(float)K3V);

  // ---- readout MLP ----
  k_mlp<<<BV, 128, 0, stream>>>(x1g, x2g, x3g, l1_w, l1_b, l2_w, l2_b, l3_w, l3_b, out);
}

// Round 2
// 3863.164 us; speedup vs baseline: 1.0322x; 1.0322x over previous
//
#include <hip/hip_runtime.h>
#include <math.h>
#include <stdint.h>

#define NBV 65536
#define EV  1048576
#define BV  128
#define K1V 410
#define K2V 205
#define K3V 103
#define NEG_BIG (-1.0e38f)

__device__ __forceinline__ float lrelu(float x){ return x > 0.f ? x : 0.2f*x; }

// async global->LDS 16B copy: LDS dest is wave-uniform base + lane*16,
// global src is per-lane. vmcnt-tracked; drained by the compiler's
// s_waitcnt before s_barrier.
typedef __attribute__((address_space(3))) unsigned int lds_u32;
typedef __attribute__((address_space(1))) unsigned int glb_u32;
__device__ __forceinline__ void lds_load16(const float* g, float* l){
  __builtin_amdgcn_global_load_lds((const glb_u32*)(uintptr_t)g,
                                   (lds_u32*)(uintptr_t)l, 16, 0, 0);
}

// ---------------- diagnostics sentinel ----------------
__global__ void k_sentinel(float* out, float v){
  int i = threadIdx.x;
  if (i < 128) out[i] = v;
}

// ---------------- utility ----------------
__global__ void k_fill1(float* p, int n){
  int i = blockIdx.x*blockDim.x + threadIdx.x;
  if (i < n) p[i] = 1.f;
}

__global__ void k_zero_i(int* p, int n){
  int i = blockIdx.x*blockDim.x + threadIdx.x;
  if (i < n) p[i] = 0;
}

// ---------------- CSR build (int atomics only) ----------------
__global__ void k_hist(const int* dst, int* dcnt){
  int e = blockIdx.x*blockDim.x + threadIdx.x;
  if (e < EV) atomicAdd(&dcnt[dst[e]], 1);
}

__global__ void k_scan1(const int* dcnt, int* rp, int* bsum){
  __shared__ int sc[256];
  int t = threadIdx.x, i = blockIdx.x*256 + t;
  int v = dcnt[i];
  sc[t] = v; __syncthreads();
  for (int o = 1; o < 256; o <<= 1){
    int x = (t >= o) ? sc[t-o] : 0;
    __syncthreads();
    sc[t] += x;
    __syncthreads();
  }
  rp[i] = sc[t];
  if (t == 255) bsum[blockIdx.x] = sc[t];
}

__global__ void k_scan2(int* bsum){
  __shared__ int sc[256];
  int t = threadIdx.x;
  int v = bsum[t];
  sc[t] = v; __syncthreads();
  for (int o = 1; o < 256; o <<= 1){
    int x = (t >= o) ? sc[t-o] : 0;
    __syncthreads();
    sc[t] += x;
    __syncthreads();
  }
  bsum[t] = sc[t] - v;
}

__global__ void k_scan3(int* rp, const int* dcnt, const int* bsum){
  int t = threadIdx.x, i = blockIdx.x*256 + t;
  rp[i] = rp[i] - dcnt[i] + bsum[blockIdx.x];
  if (i == 0) rp[NBV] = EV;
}

__global__ void k_scatter(const int* src, const int* dst, const int* rp, int* fill,
                          int* csr_src, int* csr_eid){
  int e = blockIdx.x*blockDim.x + threadIdx.x;
  if (e < EV){
    int d = dst[e];
    int pos = atomicAdd(&fill[d], 1);
    int slot = rp[d] + pos;
    csr_src[slot] = src[e];
    csr_eid[slot] = e;
  }
}

// ---------------- small precomputes ----------------
__global__ void k_invnorm(const float* wv, float* outv){
  __shared__ float sc[128];
  int t = threadIdx.x;
  float v = wv[t];
  sc[t] = v*v; __syncthreads();
  for (int o = 64; o > 0; o >>= 1){ if (t < o) sc[t] += sc[t+o]; __syncthreads(); }
  if (t == 0) outv[0] = 1.f / sqrtf(sc[0]);
}

__global__ void k_ve(const float* g_we, const float* g_ae, float* ve){
  int t = threadIdx.x;
  if (t < 28){
    int ed = t >> 2, h = t & 3;
    float a = 0.f;
    for (int c = 0; c < 32; c++) a += g_we[ed*128 + h*32 + c] * g_ae[h*32 + c];
    ve[t] = a;
  }
}

__global__ void k_ale(const float* ea, const float* ve, float* ALE){
  int e = blockIdx.x*blockDim.x + threadIdx.x;
  if (e < EV){
    float a0=0.f,a1=0.f,a2=0.f,a3=0.f;
    for (int ed = 0; ed < 7; ed++){
      float x = ea[e*7 + ed];
      a0 += x*ve[ed*4+0]; a1 += x*ve[ed*4+1]; a2 += x*ve[ed*4+2]; a3 += x*ve[ed*4+3];
    }
    float4 o; o.x=a0; o.y=a1; o.z=a2; o.w=a3;
    *(float4*)&ALE[(size_t)e*4] = o;
  }
}

// ---------------- SAGE mean aggregation (XCD-swizzled, 4-deep gather) ----------------
__global__ void __launch_bounds__(256) k_sage_agg(const float* X, const float* nmask,
    const int* rp, const int* csr_src, float* AGG, int masked){
  int g = blockIdx.x & 127;
  int blk = blockIdx.x >> 7;
  int i = g*512 + blk*8 + (threadIdx.x >> 5);
  int c4 = threadIdx.x & 31;
  float ax=0.f,ay=0.f,az=0.f,aw=0.f,cnt=0.f;
  if (!masked || nmask[i] > 0.f){
    int r0 = rp[i], r1 = rp[i+1];
    int s = r0;
    for (; s + 4 <= r1; s += 4){
      int sn0 = csr_src[s+0], sn1 = csr_src[s+1], sn2 = csr_src[s+2], sn3 = csr_src[s+3];
      float4 v0 = *(const float4*)&X[((size_t)sn0 << 7) + (c4 << 2)];
      float4 v1 = *(const float4*)&X[((size_t)sn1 << 7) + (c4 << 2)];
      float4 v2 = *(const float4*)&X[((size_t)sn2 << 7) + (c4 << 2)];
      float4 v3 = *(const float4*)&X[((size_t)sn3 << 7) + (c4 << 2)];
      float nm0 = masked ? nmask[sn0] : 1.f;
      float nm1 = masked ? nmask[sn1] : 1.f;
      float nm2 = masked ? nmask[sn2] : 1.f;
      float nm3 = masked ? nmask[sn3] : 1.f;
      if (nm0 > 0.f){ ax += v0.x; ay += v0.y; az += v0.z; aw += v0.w; cnt += 1.f; }
      if (nm1 > 0.f){ ax += v1.x; ay += v1.y; az += v1.z; aw += v1.w; cnt += 1.f; }
      if (nm2 > 0.f){ ax += v2.x; ay += v2.y; az += v2.z; aw += v2.w; cnt += 1.f; }
      if (nm3 > 0.f){ ax += v3.x; ay += v3.y; az += v3.z; aw += v3.w; cnt += 1.f; }
    }
    for (; s < r1; s++){
      int sn = csr_src[s];
      float nm = masked ? nmask[sn] : 1.f;
      if (nm > 0.f){
        const float4 v = *(const float4*)&X[((size_t)sn << 7) + (c4 << 2)];
        ax += v.x; ay += v.y; az += v.z; aw += v.w; cnt += 1.f;
      }
    }
  }
  float inv = 1.f / fmaxf(cnt, 1.f);
  float4 o; o.x = ax*inv; o.y = ay*inv; o.z = az*inv; o.w = aw*inv;
  *(float4*)&AGG[((size_t)i << 7) + (c4 << 2)] = o;
}

// ---------------- dual GEMM f32, K-chunk streamed, double-buffered ----------------
// r13 post-mortem: launch_bounds(512,8) demanded 8 waves/EU -> 64-VGPR budget;
// the dual-buffer schedule needs ~75 so the compiler SPILLED the 32-reg
// accumulator (VGPR_Count=32, 4.9GB scratch traffic, 1390us). The schedule
// itself verified bit-exact. Fix: (512,6) -> 85-VGPR budget (no spill) while
// still guaranteeing 6 waves/EU = 3 blocks/CU (LDS 3x34KB fits 160KB).
__global__ void __launch_bounds__(512, 6) k_gemm(const float* A1, const float* A2,
    const float* W1, const float* W2, const float* bias,
    float* OUT, int has2, int relu, int hasb){
  __shared__ float ws[2][16][128];   // linear: global_load_lds dest (no pad!)
  __shared__ float as[2][16][140];   // transposed A chunk; 140 -> 2-way banks on write
  int t = threadIdx.x;
  int n0 = blockIdx.x * 128;
  int rowg = t >> 5;
  int colg = t & 31;
  int rb = rowg * 8;
  int jb = colg * 4;
  int an = t >> 2;              // A-stage row 0..127
  int ak = (t & 3) << 2;        // A-stage k offset {0,4,8,12}
  int wvid = t >> 6;            // wave 0..7 -> ws rows 2w,2w+1
  int ln = t & 63;
  float acc[8][4];
  #pragma unroll
  for (int r = 0; r < 8; r++)
    #pragma unroll
    for (int j = 0; j < 4; j++) acc[r][j] = 0.f;
  int nmat = has2 ? 2 : 1;
  for (int m = 0; m < nmat; m++){
    const float* A = (m == 0) ? A1 : A2;
    const float* W = (m == 0) ? W1 : W2;
    const float* Arow  = A + (((size_t)(n0 + an)) << 7) + ak;
    const float* Wlane = W + wvid*256 + ln*4;
    // stage chunk 0 (previous matrix's readers are past the c=7 barrier)
    float4 rA = *(const float4*)Arow;
    lds_load16(Wlane, &ws[0][wvid*2][0]);
    as[0][ak+0][an] = rA.x;
    as[0][ak+1][an] = rA.y;
    as[0][ak+2][an] = rA.z;
    as[0][ak+3][an] = rA.w;
    __syncthreads();   // drains vmcnt (ws chunk0) + lgkm (as chunk0)
    #pragma unroll 2
    for (int c = 0; c < 8; c++){
      int cur = c & 1, nxt = cur ^ 1;
      if (c < 7){
        rA = *(const float4*)(Arow + (c+1)*16);            // issue early
        lds_load16(Wlane + (c+1)*2048, &ws[nxt][wvid*2][0]); // async, lands by barrier
      }
      #pragma unroll
      for (int kk = 0; kk < 16; kk++){
        float4 w4 = *(const float4*)&ws[cur][kk][jb];
        float4 aL = *(const float4*)&as[cur][kk][rb];
        float4 aH = *(const float4*)&as[cur][kk][rb+4];
        float a0=aL.x,a1=aL.y,a2=aL.z,a3=aL.w,a4=aH.x,a5=aH.y,a6=aH.z,a7=aH.w;
        acc[0][0]+=a0*w4.x; acc[0][1]+=a0*w4.y; acc[0][2]+=a0*w4.z; acc[0][3]+=a0*w4.w;
        acc[1][0]+=a1*w4.x; acc[1][1]+=a1*w4.y; acc[1][2]+=a1*w4.z; acc[1][3]+=a1*w4.w;
        acc[2][0]+=a2*w4.x; acc[2][1]+=a2*w4.y; acc[2][2]+=a2*w4.z; acc[2][3]+=a2*w4.w;
        acc[3][0]+=a3*w4.x; acc[3][1]+=a3*w4.y; acc[3][2]+=a3*w4.z; acc[3][3]+=a3*w4.w;
        acc[4][0]+=a4*w4.x; acc[4][1]+=a4*w4.y; acc[4][2]+=a4*w4.z; acc[4][3]+=a4*w4.w;
        acc[5][0]+=a5*w4.x; acc[5][1]+=a5*w4.y; acc[5][2]+=a5*w4.z; acc[5][3]+=a5*w4.w;
        acc[6][0]+=a6*w4.x; acc[6][1]+=a6*w4.y; acc[6][2]+=a6*w4.z; acc[6][3]+=a6*w4.w;
        acc[7][0]+=a7*w4.x; acc[7][1]+=a7*w4.y; acc[7][2]+=a7*w4.z; acc[7][3]+=a7*w4.w;
      }
      if (c < 7){                    // write-late: HBM/L2 latency hid under compute
        as[nxt][ak+0][an] = rA.x;
        as[nxt][ak+1][an] = rA.y;
        as[nxt][ak+2][an] = rA.z;
        as[nxt][ak+3][an] = rA.w;
      }
      __syncthreads();               // single barrier per chunk
    }
  }
  float bj0=0.f,bj1=0.f,bj2=0.f,bj3=0.f;
  if (hasb){
    bj0 = bias[jb+0]; bj1 = bias[jb+1]; bj2 = bias[jb+2]; bj3 = bias[jb+3];
  }
  for (int r = 0; r < 8; r++){
    float4 o;
    o.x = acc[r][0]+bj0; o.y = acc[r][1]+bj1; o.z = acc[r][2]+bj2; o.w = acc[r][3]+bj3;
    if (relu){
      o.x = fmaxf(o.x,0.f); o.y = fmaxf(o.y,0.f); o.z = fmaxf(o.z,0.f); o.w = fmaxf(o.w,0.f);
    }
    *(float4*)&OUT[((size_t)(n0+rb+r) << 7) + jb] = o;
  }
}

// ---------------- scores (32 lanes/node, shfl reduce) ----------------
__global__ void __launch_bounds__(256) k_score1(const float* X, const float* pw, const float* invn, float* s){
  int gid = blockIdx.x*256 + threadIdx.x;
  int i = gid >> 5, c4 = gid & 31;
  float4 v = *(const float4*)&X[((size_t)i << 7) + (c4 << 2)];
  float4 wv = *(const float4*)&pw[c4 << 2];
  float a = v.x*wv.x + v.y*wv.y + v.z*wv.z + v.w*wv.w;
  for (int o = 16; o > 0; o >>= 1) a += __shfl_down(a, o, 32);
  if (c4 == 0) s[i] = tanhf(a * invn[0]);
}

__global__ void __launch_bounds__(256) k_qr(const float* X, const float* wrel, const float* wroot,
                                            float* q, float* r){
  int gid = blockIdx.x*256 + threadIdx.x;
  int i = gid >> 5, c4 = gid & 31;
  float4 v = *(const float4*)&X[((size_t)i << 7) + (c4 << 2)];
  float4 wa = *(const float4*)&wrel[c4 << 2];
  float4 wb = *(const float4*)&wroot[c4 << 2];
  float aq = v.x*wa.x + v.y*wa.y + v.z*wa.z + v.w*wa.w;
  float ar = v.x*wb.x + v.y*wb.y + v.z*wb.z + v.w*wb.w;
  for (int o = 16; o > 0; o >>= 1){
    aq += __shfl_down(aq, o, 32);
    ar += __shfl_down(ar, o, 32);
  }
  if (c4 == 0){ q[i] = aq; r[i] = ar; }
}

__global__ void k_gconv(const float* q, const float* r, const float* nmask,
    const int* rp, const int* csr_src, const float* brel, float* s){
  int i = blockIdx.x*blockDim.x + threadIdx.x;
  if (i >= NBV) return;
  float acc = 0.f;
  if (nmask[i] > 0.f){
    int r0 = rp[i], r1 = rp[i+1];
    int t2 = r0;
    for (; t2 + 4 <= r1; t2 += 4){
      int sn0 = csr_src[t2+0], sn1 = csr_src[t2+1], sn2 = csr_src[t2+2], sn3 = csr_src[t2+3];
      float nm0 = nmask[sn0], nm1 = nmask[sn1], nm2 = nmask[sn2], nm3 = nmask[sn3];
      float q0 = q[sn0], q1 = q[sn1], q2 = q[sn2], q3 = q[sn3];
      if (nm0 > 0.f) acc += q0;
      if (nm1 > 0.f) acc += q1;
      if (nm2 > 0.f) acc += q2;
      if (nm3 > 0.f) acc += q3;
    }
    for (; t2 < r1; t2++){
      int sn = csr_src[t2];
      if (nmask[sn] > 0.f) acc += q[sn];
    }
  }
  s[i] = tanhf(acc + brel[0] + r[i]);
}

// ---------------- top-k pool (stable tie-break == jax.lax.top_k) ----------------
__global__ void __launch_bounds__(512) k_pool(const float* s, float* nmask, float* sel, int K){
  __shared__ float sc[512];
  int b = blockIdx.x, t = threadIdx.x;
  int i = b*512 + t;
  float nm = nmask[i];
  float sv = s[i];
  float ms = (nm > 0.f) ? sv : NEG_BIG;
  sc[t] = ms;
  __syncthreads();
  int rank = 0;
  for (int j = 0; j < 512; j++){
    float o = sc[j];
    rank += ((o > ms) || (o == ms && j < t)) ? 1 : 0;
  }
  bool selb = rank < K;
  nmask[i] = selb ? 1.f : 0.f;
  sel[i] = selb ? sv : 0.f;
}

// scale kept rows by score (in place) + gap partials — no atomics.
__global__ void __launch_bounds__(128) k_scale_part(float* X, const float* sel, float* part){
  int b = blockIdx.x >> 3, q = blockIdx.x & 7, c = threadIdx.x;
  float acc = 0.f;
  for (int n = q*64; n < q*64 + 64; n++){
    int i = b*512 + n;
    float v = X[((size_t)i << 7) + c] * sel[i];
    X[((size_t)i << 7) + c] = v;
    acc += v;
  }
  part[(size_t)blockIdx.x*128 + c] = acc;
}

__global__ void __launch_bounds__(128) k_gap_final(const float* part, float* gap, float invK){
  int b = blockIdx.x, c = threadIdx.x;
  float s = 0.f;
  for (int q = 0; q < 8; q++) s += part[(size_t)(b*8+q)*128 + c];
  gap[b*128 + c] = s * invK;
}

// ---------------- GAT pieces ----------------
__global__ void k_heads(const float* xs, const float* a_s, const float* a_d,
                        float* alS, float* alD){
  int gid = blockIdx.x*blockDim.x + threadIdx.x;
  int i = gid >> 2, h = gid & 3;
  if (i >= NBV) return;
  const float4* xr = (const float4*)&xs[((size_t)i << 7) + h*32];
  const float4* wa = (const float4*)&a_s[h*32];
  const float4* wd = (const float4*)&a_d[h*32];
  float as_ = 0.f, ad_ = 0.f;
  for (int c4 = 0; c4 < 8; c4++){
    float4 v = xr[c4]; float4 A = wa[c4]; float4 D = wd[c4];
    as_ += v.x*A.x + v.y*A.y + v.z*A.z + v.w*A.w;
    ad_ += v.x*D.x + v.y*D.y + v.z*D.z + v.w*D.w;
  }
  alS[gid] = as_; alD[gid] = ad_;
}

// edge-attr masked mean: per-block partials (no atomics)
__global__ void __launch_bounds__(256) k_ea_part(const float* ea, const int* srcA, const int* dstA,
    const float* nmask, float* part){
  float p[8] = {0.f,0.f,0.f,0.f,0.f,0.f,0.f,0.f};
  for (int e = blockIdx.x*256 + threadIdx.x; e < EV; e += 256*256){
    if (nmask[srcA[e]] > 0.f && nmask[dstA[e]] > 0.f){
      for (int d = 0; d < 7; d++) p[d] += ea[e*7 + d];
      p[7] += 1.f;
    }
  }
  __shared__ float red[256];
  for (int comp = 0; comp < 8; comp++){
    red[threadIdx.x] = p[comp]; __syncthreads();
    for (int o = 128; o > 0; o >>= 1){ if (threadIdx.x < o) red[threadIdx.x] += red[threadIdx.x + o]; __syncthreads(); }
    if (threadIdx.x == 0) part[blockIdx.x*8 + comp] = red[0];
    __syncthreads();
  }
}

__global__ void k_ea_final(const float* part, float* easum){
  int h = threadIdx.x;
  if (h < 8){
    float s = 0.f;
    for (int b = 0; b < 256; b++) s += part[b*8 + h];
    easum[h] = s;
  }
}

__global__ void k_alse(const float* easum, const float* ve, float* alse){
  if (threadIdx.x == 0 && blockIdx.x == 0){
    float cnt = fmaxf(easum[7], 1.f);
    for (int h = 0; h < 4; h++){
      float s = 0.f;
      for (int ed = 0; ed < 7; ed++) s += (easum[ed]/cnt) * ve[ed*4 + h];
      alse[h] = s;
    }
  }
}

// GAT: 32 threads/node, XCD-swizzled, 4-deep gathers + in-order online softmax.
__global__ void __launch_bounds__(256) k_gat(const float* xs, const float* alS, const float* alD,
    const float* ALE, const float* nmask, const int* rp, const int* csr_src,
    const int* csr_eid, const float* alse, const float* g_b, float* OUT){
  int g = blockIdx.x & 127;
  int blk = blockIdx.x >> 7;
  int i = g*512 + blk*8 + (threadIdx.x >> 5);
  int lane = threadIdx.x & 31;
  int h = lane >> 3;
  int cidx = h*8 + (lane & 7);
  float nmi = nmask[i];
  const float4* xs4 = (const float4*)xs;
  float m = 0.f, den = 0.f;
  float4 acc; acc.x=0.f; acc.y=0.f; acc.z=0.f; acc.w=0.f;
  if (nmi > 0.f){
    float ald_i = alD[i*4 + h];
    m = lrelu(alS[i*4 + h] + ald_i + alse[h]);   // aself
    den = 1.f;
    acc = xs4[(size_t)i*32 + cidx];
    int r0 = rp[i], r1 = rp[i+1];
    int s = r0;
    for (; s + 4 <= r1; s += 4){
      int sn0 = csr_src[s+0], sn1 = csr_src[s+1], sn2 = csr_src[s+2], sn3 = csr_src[s+3];
      int e0 = csr_eid[s+0], e1 = csr_eid[s+1], e2 = csr_eid[s+2], e3 = csr_eid[s+3];
      float nm0 = nmask[sn0], nm1 = nmask[sn1], nm2 = nmask[sn2], nm3 = nmask[sn3];
      float al0 = alS[sn0*4 + h], al1 = alS[sn1*4 + h], al2 = alS[sn2*4 + h], al3 = alS[sn3*4 + h];
      float ae0 = ALE[(size_t)e0*4 + h], ae1 = ALE[(size_t)e1*4 + h];
      float ae2 = ALE[(size_t)e2*4 + h], ae3 = ALE[(size_t)e3*4 + h];
      float4 v0 = xs4[(size_t)sn0*32 + cidx];
      float4 v1 = xs4[(size_t)sn1*32 + cidx];
      float4 v2 = xs4[(size_t)sn2*32 + cidx];
      float4 v3 = xs4[(size_t)sn3*32 + cidx];
      if (nm0 > 0.f){
        float a = lrelu(al0 + ald_i + ae0);
        float mn = fmaxf(m, a); float pm = expf(m - mn); float pa = expf(a - mn);
        den = den*pm + pa;
        acc.x = acc.x*pm + pa*v0.x; acc.y = acc.y*pm + pa*v0.y;
        acc.z = acc.z*pm + pa*v0.z; acc.w = acc.w*pm + pa*v0.w;
        m = mn;
      }
      if (nm1 > 0.f){
        float a = lrelu(al1 + ald_i + ae1);
        float mn = fmaxf(m, a); float pm = expf(m - mn); float pa = expf(a - mn);
        den = den*pm + pa;
        acc.x = acc.x*pm + pa*v1.x; acc.y = acc.y*pm + pa*v1.y;
        acc.z = acc.z*pm + pa*v1.z; acc.w = acc.w*pm + pa*v1.w;
        m = mn;
      }
      if (nm2 > 0.f){
        float a = lrelu(al2 + ald_i + ae2);
        float mn = fmaxf(m, a); float pm = expf(m - mn); float pa = expf(a - mn);
        den = den*pm + pa;
        acc.x = acc.x*pm + pa*v2.x; acc.y = acc.y*pm + pa*v2.y;
        acc.z = acc.z*pm + pa*v2.z; acc.w = acc.w*pm + pa*v2.w;
        m = mn;
      }
      if (nm3 > 0.f){
        float a = lrelu(al3 + ald_i + ae3);
        float mn = fmaxf(m, a); float pm = expf(m - mn); float pa = expf(a - mn);
        den = den*pm + pa;
        acc.x = acc.x*pm + pa*v3.x; acc.y = acc.y*pm + pa*v3.y;
        acc.z = acc.z*pm + pa*v3.z; acc.w = acc.w*pm + pa*v3.w;
        m = mn;
      }
    }
    for (; s < r1; s++){
      int sn = csr_src[s];
      if (nmask[sn] > 0.f){
        float a = lrelu(alS[sn*4 + h] + ald_i + ALE[(size_t)csr_eid[s]*4 + h]);
        float4 v = xs4[(size_t)sn*32 + cidx];
        float mn = fmaxf(m, a); float pm = expf(m - mn); float pa = expf(a - mn);
        den = den*pm + pa;
        acc.x = acc.x*pm + pa*v.x; acc.y = acc.y*pm + pa*v.y;
        acc.z = acc.z*pm + pa*v.z; acc.w = acc.w*pm + pa*v.w;
        m = mn;
      }
    }
  }
  den = fmaxf(den, 1e-16f);
  float rd = 1.f/den;
  int cb = cidx << 2;
  float4 o;
  o.x = fmaxf(acc.x*rd + g_b[cb+0], 0.f);
  o.y = fmaxf(acc.y*rd + g_b[cb+1], 0.f);
  o.z = fmaxf(acc.z*rd + g_b[cb+2], 0.f);
  o.w = fmaxf(acc.w*rd + g_b[cb+3], 0.f);
  *(float4*)&OUT[((size_t)i << 7) + cb] = o;
}

// ---------------- final MLP ----------------
__global__ void __launch_bounds__(128) k_mlp(const float* x1g, const float* x2g, const float* x3g,
    const float* l1w, const float* l1b, const float* l2w, const float* l2b,
    const float* l3w, const float* l3b, float* out){
  __shared__ float hh[128];
  __shared__ float h2[128];
  __shared__ float h3[64];
  int b = blockIdx.x, t = threadIdx.x;
  hh[t] = x1g[b*128 + t] + x2g[b*128 + t] + x3g[b*128 + t];
  __syncthreads();
  float a = l1b[t];
  for (int k = 0; k < 128; k++) a += hh[k] * l1w[k*128 + t];
  h2[t] = fmaxf(a, 0.f);
  __syncthreads();
  if (t < 64){
    float a2 = l2b[t];
    for (int k = 0; k < 128; k++) a2 += h2[k] * l2w[k*64 + t];
    h3[t] = fmaxf(a2, 0.f);
  }
  __syncthreads();
  if (t == 0){
    float z = l3b[0];
    for (int k = 0; k < 64; k++) z += h3[k] * l3w[k];
    out[b] = 1.f/(1.f + expf(-z));
  }
}

// ---------------- launch ----------------
extern "C" void kernel_launch(void* const* d_in, const int* in_sizes, int n_in,
                              void* d_out, int out_size, void* d_ws, size_t ws_size,
                              hipStream_t stream){
  const float* x       = (const float*)d_in[0];
  const int*   ei      = (const int*)d_in[1];
  const float* ea      = (const float*)d_in[2];
  const float* c1_wl   = (const float*)d_in[3];
  const float* c1_bl   = (const float*)d_in[4];
  const float* c1_wr   = (const float*)d_in[5];
  const float* p1_w    = (const float*)d_in[6];
  const float* c2_wl   = (const float*)d_in[7];
  const float* c2_bl   = (const float*)d_in[8];
  const float* c2_wr   = (const float*)d_in[9];
  const float* p2_wrel = (const float*)d_in[10];
  const float* p2_brel = (const float*)d_in[11];
  const float* p2_wroot= (const float*)d_in[12];
  const float* g_w     = (const float*)d_in[13];
  const float* g_as    = (const float*)d_in[14];
  const float* g_ad    = (const float*)d_in[15];
  const float* g_we    = (const float*)d_in[16];
  const float* g_ae    = (const float*)d_in[17];
  const float* g_b     = (const float*)d_in[18];
  const float* p3_wrel = (const float*)d_in[19];
  const float* p3_brel = (const float*)d_in[20];
  const float* p3_wroot= (const float*)d_in[21];
  const float* l1_w    = (const float*)d_in[22];
  const float* l1_b    = (const float*)d_in[23];
  const float* l2_w    = (const float*)d_in[24];
  const float* l2_b    = (const float*)d_in[25];
  const float* l3_w    = (const float*)d_in[26];
  const float* l3_b    = (const float*)d_in[27];
  float* out = (float*)d_out;
  (void)in_sizes; (void)n_in; (void)out_size;

  // Workspace layout (f32, ~137 MB)
  char* w = (char*)d_ws;
  size_t off = 0;
  float* AGG  = (float*)(w + off); off += (size_t)NBV*128*4;
  float* F1   = (float*)(w + off); off += (size_t)NBV*128*4;
  float* F2   = (float*)(w + off); off += (size_t)NBV*128*4;
  float* ALE  = (float*)(w + off); off += (size_t)EV*4*4;
  float* sA   = (float*)(w + off); off += (size_t)NBV*4;
  float* sel  = (float*)(w + off); off += (size_t)NBV*4;
  float* qv   = (float*)(w + off); off += (size_t)NBV*4;
  float* rv   = (float*)(w + off); off += (size_t)NBV*4;
  float* nmask= (float*)(w + off); off += (size_t)NBV*4;
  float* alS  = (float*)(w + off); off += (size_t)NBV*4*4;
  float* alD  = (float*)(w + off); off += (size_t)NBV*4*4;
  float* x1g  = (float*)(w + off); off += (size_t)BV*128*4;
  float* x2g  = (float*)(w + off); off += (size_t)BV*128*4;
  float* x3g  = (float*)(w + off); off += (size_t)BV*128*4;
  float* sml  = (float*)(w + off); off += 64*4;      // [0]=invnorm [8..15]=easum [16..19]=alse [20..47]=ve
  float* eprt = (float*)(w + off); off += 2048*4;
  float* gprt = (float*)(w + off); off += (size_t)1024*128*4;
  int* csr_src = (int*)(w + off); off += (size_t)EV*4;
  int* csr_eid = (int*)(w + off); off += (size_t)EV*4;
  int* rp      = (int*)(w + off); off += (size_t)(NBV+64)*4;
  int* dcnt    = (int*)(w + off); off += (size_t)(NBV+64)*4;
  int* bsum    = (int*)(w + off); off += 1024;
  size_t needed = off;

  float sentinel = (ws_size >= needed) ? 0.125f : 0.875f;
  k_sentinel<<<1, 128, 0, stream>>>(out, sentinel);

  const int* srcA = ei;
  const int* dstA = ei + EV;

  // ---- setup ----
  k_fill1<<<NBV/256, 256, 0, stream>>>(nmask, NBV);
  k_zero_i<<<(NBV+256)/256, 256, 0, stream>>>(dcnt, NBV+1);
  k_hist<<<EV/256, 256, 0, stream>>>(dstA, dcnt);
  k_scan1<<<256, 256, 0, stream>>>(dcnt, rp, bsum);
  k_scan2<<<1, 256, 0, stream>>>(bsum);
  k_scan3<<<256, 256, 0, stream>>>(rp, dcnt, bsum);
  k_zero_i<<<(NBV+256)/256, 256, 0, stream>>>(dcnt, NBV+1);
  k_scatter<<<EV/256, 256, 0, stream>>>(srcA, dstA, rp, dcnt, csr_src, csr_eid);
  k_ve<<<1, 32, 0, stream>>>(g_we, g_ae, sml+20);
  k_ale<<<EV/256, 256, 0, stream>>>(ea, sml+20, ALE);

  // ---- block 1: SAGE -> TopK(410) -> gap  (x -> F1) ----
  k_invnorm<<<1, 128, 0, stream>>>(p1_w, sml);
  k_sage_agg<<<(NBV*32)/256, 256, 0, stream>>>(x, nmask, rp, csr_src, AGG, 0);
  k_gemm<<<NBV/128, 512, 0, stream>>>(AGG, x, c1_wl, c1_wr, c1_bl, F1, 1, 1, 1);
  k_score1<<<(NBV*32)/256, 256, 0, stream>>>(F1, p1_w, sml, sA);
  k_pool<<<BV, 512, 0, stream>>>(sA, nmask, sel, K1V);
  k_scale_part<<<BV*8, 128, 0, stream>>>(F1, sel, gprt);
  k_gap_final<<<BV, 128, 0, stream>>>(gprt, x1g, 1.f/(float)K1V);

  // ---- block 2: SAGE -> SAGPool(205) -> gap  (F1 -> F2) ----
  k_sage_agg<<<(NBV*32)/256, 256, 0, stream>>>(F1, nmask, rp, csr_src, AGG, 1);
  k_gemm<<<NBV/128, 512, 0, stream>>>(AGG, F1, c2_wl, c2_wr, c2_bl, F2, 1, 1, 1);
  k_qr<<<(NBV*32)/256, 256, 0, stream>>>(F2, p2_wrel, p2_wroot, qv, rv);
  k_gconv<<<NBV/256, 256, 0, stream>>>(qv, rv, nmask, rp, csr_src, p2_brel, sA);
  k_pool<<<BV, 512, 0, stream>>>(sA, nmask, sel, K2V);
  k_scale_part<<<BV*8, 128, 0, stream>>>(F2, sel, gprt);
  k_gap_final<<<BV, 128, 0, stream>>>(gprt, x2g, 1.f/(float)K2V);

  // ---- block 3: GAT -> SAGPool(103) -> gap  (F2 -> xs=AGG -> F1) ----
  k_gemm<<<NBV/128, 512, 0, stream>>>(F2, F2, g_w, g_w, g_b, AGG, 0, 0, 0);  // xs = F2 @ g_w
  k_heads<<<(NBV*4)/256, 256, 0, stream>>>(AGG, g_as, g_ad, alS, alD);
  k_ea_part<<<256, 256, 0, stream>>>(ea, srcA, dstA, nmask, eprt);
  k_ea_final<<<1, 64, 0, stream>>>(eprt, sml+8);
  k_alse<<<1, 64, 0, stream>>>(sml+8, sml+20, sml+16);
  k_gat<<<(NBV*32)/256, 256, 0, stream>>>(AGG, alS, alD, ALE, nmask, rp, csr_src, csr_eid, sml+16, g_b, F1);
  k_qr<<<(NBV*32)/256, 256, 0, stream>>>(F1, p3_wrel, p3_wroot, qv, rv);
  k_gconv<<<NBV/256, 256, 0, stream>>>(qv, rv, nmask, rp, csr_src, p3_brel, sA);
  k_pool<<<BV, 512, 0, stream>>>(sA, nmask, sel, K3V);
  k_scale_part<<<BV*8, 128, 0, stream>>>(F1, sel, gprt);
  k_gap_final<<<BV, 128, 0, stream>>>(gprt, x3g, 1.f/(float)K3V);

  // ---- readout MLP ----
  k_mlp<<<BV, 128, 0, stream>>>(x1g, x2g, x3g, l1_w, l1_b, l2_w, l2_b, l3_w, l3_b, out);
}

// Round 3
// 1687.733 us; speedup vs baseline: 2.3627x; 2.2890x over previous
//
#include <hip/hip_runtime.h>
#include <math.h>
#include <stdint.h>

#define NBV 65536
#define EV  1048576
#define BV  128
#define K1V 410
#define K2V 205
#define K3V 103
#define NEG_BIG (-1.0e38f)

__device__ __forceinline__ float lrelu(float x){ return x > 0.f ? x : 0.2f*x; }

// async global->LDS 16B copy: LDS dest is wave-uniform base + lane*16,
// global src is per-lane. vmcnt-tracked; drained by the compiler's
// s_waitcnt before s_barrier.
typedef __attribute__((address_space(3))) unsigned int lds_u32;
typedef __attribute__((address_space(1))) unsigned int glb_u32;
__device__ __forceinline__ void lds_load16(const float* g, float* l){
  __builtin_amdgcn_global_load_lds((const glb_u32*)(uintptr_t)g,
                                   (lds_u32*)(uintptr_t)l, 16, 0, 0);
}

// ---------------- diagnostics sentinel ----------------
__global__ void k_sentinel(float* out, float v){
  int i = threadIdx.x;
  if (i < 128) out[i] = v;
}

// ---------------- utility ----------------
__global__ void k_fill1(float* p, int n){
  int i = blockIdx.x*blockDim.x + threadIdx.x;
  if (i < n) p[i] = 1.f;
}

__global__ void k_zero_i(int* p, int n){
  int i = blockIdx.x*blockDim.x + threadIdx.x;
  if (i < n) p[i] = 0;
}

// ---------------- CSR build (int atomics only) ----------------
__global__ void k_hist(const int* dst, int* dcnt){
  int e = blockIdx.x*blockDim.x + threadIdx.x;
  if (e < EV) atomicAdd(&dcnt[dst[e]], 1);
}

__global__ void k_scan1(const int* dcnt, int* rp, int* bsum){
  __shared__ int sc[256];
  int t = threadIdx.x, i = blockIdx.x*256 + t;
  int v = dcnt[i];
  sc[t] = v; __syncthreads();
  for (int o = 1; o < 256; o <<= 1){
    int x = (t >= o) ? sc[t-o] : 0;
    __syncthreads();
    sc[t] += x;
    __syncthreads();
  }
  rp[i] = sc[t];
  if (t == 255) bsum[blockIdx.x] = sc[t];
}

__global__ void k_scan2(int* bsum){
  __shared__ int sc[256];
  int t = threadIdx.x;
  int v = bsum[t];
  sc[t] = v; __syncthreads();
  for (int o = 1; o < 256; o <<= 1){
    int x = (t >= o) ? sc[t-o] : 0;
    __syncthreads();
    sc[t] += x;
    __syncthreads();
  }
  bsum[t] = sc[t] - v;
}

__global__ void k_scan3(int* rp, const int* dcnt, const int* bsum){
  int t = threadIdx.x, i = blockIdx.x*256 + t;
  rp[i] = rp[i] - dcnt[i] + bsum[blockIdx.x];
  if (i == 0) rp[NBV] = EV;
}

__global__ void k_scatter(const int* src, const int* dst, const int* rp, int* fill,
                          int* csr_src, int* csr_eid){
  int e = blockIdx.x*blockDim.x + threadIdx.x;
  if (e < EV){
    int d = dst[e];
    int pos = atomicAdd(&fill[d], 1);
    int slot = rp[d] + pos;
    csr_src[slot] = src[e];
    csr_eid[slot] = e;
  }
}

// ---------------- small precomputes ----------------
__global__ void k_invnorm(const float* wv, float* outv){
  __shared__ float sc[128];
  int t = threadIdx.x;
  float v = wv[t];
  sc[t] = v*v; __syncthreads();
  for (int o = 64; o > 0; o >>= 1){ if (t < o) sc[t] += sc[t+o]; __syncthreads(); }
  if (t == 0) outv[0] = 1.f / sqrtf(sc[0]);
}

__global__ void k_ve(const float* g_we, const float* g_ae, float* ve){
  int t = threadIdx.x;
  if (t < 28){
    int ed = t >> 2, h = t & 3;
    float a = 0.f;
    for (int c = 0; c < 32; c++) a += g_we[ed*128 + h*32 + c] * g_ae[h*32 + c];
    ve[t] = a;
  }
}

__global__ void k_ale(const float* ea, const float* ve, float* ALE){
  int e = blockIdx.x*blockDim.x + threadIdx.x;
  if (e < EV){
    float a0=0.f,a1=0.f,a2=0.f,a3=0.f;
    for (int ed = 0; ed < 7; ed++){
      float x = ea[e*7 + ed];
      a0 += x*ve[ed*4+0]; a1 += x*ve[ed*4+1]; a2 += x*ve[ed*4+2]; a3 += x*ve[ed*4+3];
    }
    float4 o; o.x=a0; o.y=a1; o.z=a2; o.w=a3;
    *(float4*)&ALE[(size_t)e*4] = o;
  }
}

// ---------------- SAGE mean aggregation (XCD-swizzled, 4-deep gather) ----------------
__global__ void __launch_bounds__(256) k_sage_agg(const float* X, const float* nmask,
    const int* rp, const int* csr_src, float* AGG, int masked){
  int g = blockIdx.x & 127;
  int blk = blockIdx.x >> 7;
  int i = g*512 + blk*8 + (threadIdx.x >> 5);
  int c4 = threadIdx.x & 31;
  float ax=0.f,ay=0.f,az=0.f,aw=0.f,cnt=0.f;
  if (!masked || nmask[i] > 0.f){
    int r0 = rp[i], r1 = rp[i+1];
    int s = r0;
    for (; s + 4 <= r1; s += 4){
      int sn0 = csr_src[s+0], sn1 = csr_src[s+1], sn2 = csr_src[s+2], sn3 = csr_src[s+3];
      float4 v0 = *(const float4*)&X[((size_t)sn0 << 7) + (c4 << 2)];
      float4 v1 = *(const float4*)&X[((size_t)sn1 << 7) + (c4 << 2)];
      float4 v2 = *(const float4*)&X[((size_t)sn2 << 7) + (c4 << 2)];
      float4 v3 = *(const float4*)&X[((size_t)sn3 << 7) + (c4 << 2)];
      float nm0 = masked ? nmask[sn0] : 1.f;
      float nm1 = masked ? nmask[sn1] : 1.f;
      float nm2 = masked ? nmask[sn2] : 1.f;
      float nm3 = masked ? nmask[sn3] : 1.f;
      if (nm0 > 0.f){ ax += v0.x; ay += v0.y; az += v0.z; aw += v0.w; cnt += 1.f; }
      if (nm1 > 0.f){ ax += v1.x; ay += v1.y; az += v1.z; aw += v1.w; cnt += 1.f; }
      if (nm2 > 0.f){ ax += v2.x; ay += v2.y; az += v2.z; aw += v2.w; cnt += 1.f; }
      if (nm3 > 0.f){ ax += v3.x; ay += v3.y; az += v3.z; aw += v3.w; cnt += 1.f; }
    }
    for (; s < r1; s++){
      int sn = csr_src[s];
      float nm = masked ? nmask[sn] : 1.f;
      if (nm > 0.f){
        const float4 v = *(const float4*)&X[((size_t)sn << 7) + (c4 << 2)];
        ax += v.x; ay += v.y; az += v.z; aw += v.w; cnt += 1.f;
      }
    }
  }
  float inv = 1.f / fmaxf(cnt, 1.f);
  float4 o; o.x = ax*inv; o.y = ay*inv; o.z = az*inv; o.w = aw*inv;
  *(float4*)&AGG[((size_t)i << 7) + (c4 << 2)] = o;
}

// ---------------- dual GEMM f32, K-chunk streamed, double-buffered ----------------
// r13/r14 post-mortem: on THIS toolchain __launch_bounds__ arg2 behaves as
// CUDA-style min-BLOCKS-per-CU: arg2=8 -> 16 waves/SIMD -> 32-VGPR budget
// (VGPR_Count=32, spill); arg2=6 -> 12 waves/SIMD -> 40 VGPR (spill). Both
// measured exactly. Fix: NO second arg (R0's form compiled to 64 VGPR, no
// spill). Compiler allocates what the dual-buffer schedule needs (~75),
// occupancy lands at 5-6 waves/EU, LDS 34KB still allows 3+ blocks/CU.
__global__ void __launch_bounds__(512) k_gemm(const float* A1, const float* A2,
    const float* W1, const float* W2, const float* bias,
    float* OUT, int has2, int relu, int hasb){
  __shared__ float ws[2][16][128];   // linear: global_load_lds dest (no pad!)
  __shared__ float as[2][16][140];   // transposed A chunk; 140 -> 2-way banks on write
  int t = threadIdx.x;
  int n0 = blockIdx.x * 128;
  int rowg = t >> 5;
  int colg = t & 31;
  int rb = rowg * 8;
  int jb = colg * 4;
  int an = t >> 2;              // A-stage row 0..127
  int ak = (t & 3) << 2;        // A-stage k offset {0,4,8,12}
  int wvid = t >> 6;            // wave 0..7 -> ws rows 2w,2w+1
  int ln = t & 63;
  float acc[8][4];
  #pragma unroll
  for (int r = 0; r < 8; r++)
    #pragma unroll
    for (int j = 0; j < 4; j++) acc[r][j] = 0.f;
  int nmat = has2 ? 2 : 1;
  for (int m = 0; m < nmat; m++){
    const float* A = (m == 0) ? A1 : A2;
    const float* W = (m == 0) ? W1 : W2;
    const float* Arow  = A + (((size_t)(n0 + an)) << 7) + ak;
    const float* Wlane = W + wvid*256 + ln*4;
    // stage chunk 0 (previous matrix's readers are past the c=7 barrier)
    float4 rA = *(const float4*)Arow;
    lds_load16(Wlane, &ws[0][wvid*2][0]);
    as[0][ak+0][an] = rA.x;
    as[0][ak+1][an] = rA.y;
    as[0][ak+2][an] = rA.z;
    as[0][ak+3][an] = rA.w;
    __syncthreads();   // drains vmcnt (ws chunk0) + lgkm (as chunk0)
    #pragma unroll 2
    for (int c = 0; c < 8; c++){
      int cur = c & 1, nxt = cur ^ 1;
      if (c < 7){
        rA = *(const float4*)(Arow + (c+1)*16);            // issue early
        lds_load16(Wlane + (c+1)*2048, &ws[nxt][wvid*2][0]); // async, lands by barrier
      }
      #pragma unroll
      for (int kk = 0; kk < 16; kk++){
        float4 w4 = *(const float4*)&ws[cur][kk][jb];
        float4 aL = *(const float4*)&as[cur][kk][rb];
        float4 aH = *(const float4*)&as[cur][kk][rb+4];
        float a0=aL.x,a1=aL.y,a2=aL.z,a3=aL.w,a4=aH.x,a5=aH.y,a6=aH.z,a7=aH.w;
        acc[0][0]+=a0*w4.x; acc[0][1]+=a0*w4.y; acc[0][2]+=a0*w4.z; acc[0][3]+=a0*w4.w;
        acc[1][0]+=a1*w4.x; acc[1][1]+=a1*w4.y; acc[1][2]+=a1*w4.z; acc[1][3]+=a1*w4.w;
        acc[2][0]+=a2*w4.x; acc[2][1]+=a2*w4.y; acc[2][2]+=a2*w4.z; acc[2][3]+=a2*w4.w;
        acc[3][0]+=a3*w4.x; acc[3][1]+=a3*w4.y; acc[3][2]+=a3*w4.z; acc[3][3]+=a3*w4.w;
        acc[4][0]+=a4*w4.x; acc[4][1]+=a4*w4.y; acc[4][2]+=a4*w4.z; acc[4][3]+=a4*w4.w;
        acc[5][0]+=a5*w4.x; acc[5][1]+=a5*w4.y; acc[5][2]+=a5*w4.z; acc[5][3]+=a5*w4.w;
        acc[6][0]+=a6*w4.x; acc[6][1]+=a6*w4.y; acc[6][2]+=a6*w4.z; acc[6][3]+=a6*w4.w;
        acc[7][0]+=a7*w4.x; acc[7][1]+=a7*w4.y; acc[7][2]+=a7*w4.z; acc[7][3]+=a7*w4.w;
      }
      if (c < 7){                    // write-late: HBM/L2 latency hid under compute
        as[nxt][ak+0][an] = rA.x;
        as[nxt][ak+1][an] = rA.y;
        as[nxt][ak+2][an] = rA.z;
        as[nxt][ak+3][an] = rA.w;
      }
      __syncthreads();               // single barrier per chunk
    }
  }
  float bj0=0.f,bj1=0.f,bj2=0.f,bj3=0.f;
  if (hasb){
    bj0 = bias[jb+0]; bj1 = bias[jb+1]; bj2 = bias[jb+2]; bj3 = bias[jb+3];
  }
  for (int r = 0; r < 8; r++){
    float4 o;
    o.x = acc[r][0]+bj0; o.y = acc[r][1]+bj1; o.z = acc[r][2]+bj2; o.w = acc[r][3]+bj3;
    if (relu){
      o.x = fmaxf(o.x,0.f); o.y = fmaxf(o.y,0.f); o.z = fmaxf(o.z,0.f); o.w = fmaxf(o.w,0.f);
    }
    *(float4*)&OUT[((size_t)(n0+rb+r) << 7) + jb] = o;
  }
}

// ---------------- scores (32 lanes/node, shfl reduce) ----------------
__global__ void __launch_bounds__(256) k_score1(const float* X, const float* pw, const float* invn, float* s){
  int gid = blockIdx.x*256 + threadIdx.x;
  int i = gid >> 5, c4 = gid & 31;
  float4 v = *(const float4*)&X[((size_t)i << 7) + (c4 << 2)];
  float4 wv = *(const float4*)&pw[c4 << 2];
  float a = v.x*wv.x + v.y*wv.y + v.z*wv.z + v.w*wv.w;
  for (int o = 16; o > 0; o >>= 1) a += __shfl_down(a, o, 32);
  if (c4 == 0) s[i] = tanhf(a * invn[0]);
}

__global__ void __launch_bounds__(256) k_qr(const float* X, const float* wrel, const float* wroot,
                                            float* q, float* r){
  int gid = blockIdx.x*256 + threadIdx.x;
  int i = gid >> 5, c4 = gid & 31;
  float4 v = *(const float4*)&X[((size_t)i << 7) + (c4 << 2)];
  float4 wa = *(const float4*)&wrel[c4 << 2];
  float4 wb = *(const float4*)&wroot[c4 << 2];
  float aq = v.x*wa.x + v.y*wa.y + v.z*wa.z + v.w*wa.w;
  float ar = v.x*wb.x + v.y*wb.y + v.z*wb.z + v.w*wb.w;
  for (int o = 16; o > 0; o >>= 1){
    aq += __shfl_down(aq, o, 32);
    ar += __shfl_down(ar, o, 32);
  }
  if (c4 == 0){ q[i] = aq; r[i] = ar; }
}

__global__ void k_gconv(const float* q, const float* r, const float* nmask,
    const int* rp, const int* csr_src, const float* brel, float* s){
  int i = blockIdx.x*blockDim.x + threadIdx.x;
  if (i >= NBV) return;
  float acc = 0.f;
  if (nmask[i] > 0.f){
    int r0 = rp[i], r1 = rp[i+1];
    int t2 = r0;
    for (; t2 + 4 <= r1; t2 += 4){
      int sn0 = csr_src[t2+0], sn1 = csr_src[t2+1], sn2 = csr_src[t2+2], sn3 = csr_src[t2+3];
      float nm0 = nmask[sn0], nm1 = nmask[sn1], nm2 = nmask[sn2], nm3 = nmask[sn3];
      float q0 = q[sn0], q1 = q[sn1], q2 = q[sn2], q3 = q[sn3];
      if (nm0 > 0.f) acc += q0;
      if (nm1 > 0.f) acc += q1;
      if (nm2 > 0.f) acc += q2;
      if (nm3 > 0.f) acc += q3;
    }
    for (; t2 < r1; t2++){
      int sn = csr_src[t2];
      if (nmask[sn] > 0.f) acc += q[sn];
    }
  }
  s[i] = tanhf(acc + brel[0] + r[i]);
}

// ---------------- top-k pool (stable tie-break == jax.lax.top_k) ----------------
__global__ void __launch_bounds__(512) k_pool(const float* s, float* nmask, float* sel, int K){
  __shared__ float sc[512];
  int b = blockIdx.x, t = threadIdx.x;
  int i = b*512 + t;
  float nm = nmask[i];
  float sv = s[i];
  float ms = (nm > 0.f) ? sv : NEG_BIG;
  sc[t] = ms;
  __syncthreads();
  int rank = 0;
  for (int j = 0; j < 512; j++){
    float o = sc[j];
    rank += ((o > ms) || (o == ms && j < t)) ? 1 : 0;
  }
  bool selb = rank < K;
  nmask[i] = selb ? 1.f : 0.f;
  sel[i] = selb ? sv : 0.f;
}

// scale kept rows by score (in place) + gap partials — no atomics.
__global__ void __launch_bounds__(128) k_scale_part(float* X, const float* sel, float* part){
  int b = blockIdx.x >> 3, q = blockIdx.x & 7, c = threadIdx.x;
  float acc = 0.f;
  for (int n = q*64; n < q*64 + 64; n++){
    int i = b*512 + n;
    float v = X[((size_t)i << 7) + c] * sel[i];
    X[((size_t)i << 7) + c] = v;
    acc += v;
  }
  part[(size_t)blockIdx.x*128 + c] = acc;
}

__global__ void __launch_bounds__(128) k_gap_final(const float* part, float* gap, float invK){
  int b = blockIdx.x, c = threadIdx.x;
  float s = 0.f;
  for (int q = 0; q < 8; q++) s += part[(size_t)(b*8+q)*128 + c];
  gap[b*128 + c] = s * invK;
}

// ---------------- GAT pieces ----------------
__global__ void k_heads(const float* xs, const float* a_s, const float* a_d,
                        float* alS, float* alD){
  int gid = blockIdx.x*blockDim.x + threadIdx.x;
  int i = gid >> 2, h = gid & 3;
  if (i >= NBV) return;
  const float4* xr = (const float4*)&xs[((size_t)i << 7) + h*32];
  const float4* wa = (const float4*)&a_s[h*32];
  const float4* wd = (const float4*)&a_d[h*32];
  float as_ = 0.f, ad_ = 0.f;
  for (int c4 = 0; c4 < 8; c4++){
    float4 v = xr[c4]; float4 A = wa[c4]; float4 D = wd[c4];
    as_ += v.x*A.x + v.y*A.y + v.z*A.z + v.w*A.w;
    ad_ += v.x*D.x + v.y*D.y + v.z*D.z + v.w*D.w;
  }
  alS[gid] = as_; alD[gid] = ad_;
}

// edge-attr masked mean: per-block partials (no atomics)
__global__ void __launch_bounds__(256) k_ea_part(const float* ea, const int* srcA, const int* dstA,
    const float* nmask, float* part){
  float p[8] = {0.f,0.f,0.f,0.f,0.f,0.f,0.f,0.f};
  for (int e = blockIdx.x*256 + threadIdx.x; e < EV; e += 256*256){
    if (nmask[srcA[e]] > 0.f && nmask[dstA[e]] > 0.f){
      for (int d = 0; d < 7; d++) p[d] += ea[e*7 + d];
      p[7] += 1.f;
    }
  }
  __shared__ float red[256];
  for (int comp = 0; comp < 8; comp++){
    red[threadIdx.x] = p[comp]; __syncthreads();
    for (int o = 128; o > 0; o >>= 1){ if (threadIdx.x < o) red[threadIdx.x] += red[threadIdx.x + o]; __syncthreads(); }
    if (threadIdx.x == 0) part[blockIdx.x*8 + comp] = red[0];
    __syncthreads();
  }
}

__global__ void k_ea_final(const float* part, float* easum){
  int h = threadIdx.x;
  if (h < 8){
    float s = 0.f;
    for (int b = 0; b < 256; b++) s += part[b*8 + h];
    easum[h] = s;
  }
}

__global__ void k_alse(const float* easum, const float* ve, float* alse){
  if (threadIdx.x == 0 && blockIdx.x == 0){
    float cnt = fmaxf(easum[7], 1.f);
    for (int h = 0; h < 4; h++){
      float s = 0.f;
      for (int ed = 0; ed < 7; ed++) s += (easum[ed]/cnt) * ve[ed*4 + h];
      alse[h] = s;
    }
  }
}

// GAT: 32 threads/node, XCD-swizzled, 4-deep gathers + in-order online softmax.
__global__ void __launch_bounds__(256) k_gat(const float* xs, const float* alS, const float* alD,
    const float* ALE, const float* nmask, const int* rp, const int* csr_src,
    const int* csr_eid, const float* alse, const float* g_b, float* OUT){
  int g = blockIdx.x & 127;
  int blk = blockIdx.x >> 7;
  int i = g*512 + blk*8 + (threadIdx.x >> 5);
  int lane = threadIdx.x & 31;
  int h = lane >> 3;
  int cidx = h*8 + (lane & 7);
  float nmi = nmask[i];
  const float4* xs4 = (const float4*)xs;
  float m = 0.f, den = 0.f;
  float4 acc; acc.x=0.f; acc.y=0.f; acc.z=0.f; acc.w=0.f;
  if (nmi > 0.f){
    float ald_i = alD[i*4 + h];
    m = lrelu(alS[i*4 + h] + ald_i + alse[h]);   // aself
    den = 1.f;
    acc = xs4[(size_t)i*32 + cidx];
    int r0 = rp[i], r1 = rp[i+1];
    int s = r0;
    for (; s + 4 <= r1; s += 4){
      int sn0 = csr_src[s+0], sn1 = csr_src[s+1], sn2 = csr_src[s+2], sn3 = csr_src[s+3];
      int e0 = csr_eid[s+0], e1 = csr_eid[s+1], e2 = csr_eid[s+2], e3 = csr_eid[s+3];
      float nm0 = nmask[sn0], nm1 = nmask[sn1], nm2 = nmask[sn2], nm3 = nmask[sn3];
      float al0 = alS[sn0*4 + h], al1 = alS[sn1*4 + h], al2 = alS[sn2*4 + h], al3 = alS[sn3*4 + h];
      float ae0 = ALE[(size_t)e0*4 + h], ae1 = ALE[(size_t)e1*4 + h];
      float ae2 = ALE[(size_t)e2*4 + h], ae3 = ALE[(size_t)e3*4 + h];
      float4 v0 = xs4[(size_t)sn0*32 + cidx];
      float4 v1 = xs4[(size_t)sn1*32 + cidx];
      float4 v2 = xs4[(size_t)sn2*32 + cidx];
      float4 v3 = xs4[(size_t)sn3*32 + cidx];
      if (nm0 > 0.f){
        float a = lrelu(al0 + ald_i + ae0);
        float mn = fmaxf(m, a); float pm = expf(m - mn); float pa = expf(a - mn);
        den = den*pm + pa;
        acc.x = acc.x*pm + pa*v0.x; acc.y = acc.y*pm + pa*v0.y;
        acc.z = acc.z*pm + pa*v0.z; acc.w = acc.w*pm + pa*v0.w;
        m = mn;
      }
      if (nm1 > 0.f){
        float a = lrelu(al1 + ald_i + ae1);
        float mn = fmaxf(m, a); float pm = expf(m - mn); float pa = expf(a - mn);
        den = den*pm + pa;
        acc.x = acc.x*pm + pa*v1.x; acc.y = acc.y*pm + pa*v1.y;
        acc.z = acc.z*pm + pa*v1.z; acc.w = acc.w*pm + pa*v1.w;
        m = mn;
      }
      if (nm2 > 0.f){
        float a = lrelu(al2 + ald_i + ae2);
        float mn = fmaxf(m, a); float pm = expf(m - mn); float pa = expf(a - mn);
        den = den*pm + pa;
        acc.x = acc.x*pm + pa*v2.x; acc.y = acc.y*pm + pa*v2.y;
        acc.z = acc.z*pm + pa*v2.z; acc.w = acc.w*pm + pa*v2.w;
        m = mn;
      }
      if (nm3 > 0.f){
        float a = lrelu(al3 + ald_i + ae3);
        float mn = fmaxf(m, a); float pm = expf(m - mn); float pa = expf(a - mn);
        den = den*pm + pa;
        acc.x = acc.x*pm + pa*v3.x; acc.y = acc.y*pm + pa*v3.y;
        acc.z = acc.z*pm + pa*v3.z; acc.w = acc.w*pm + pa*v3.w;
        m = mn;
      }
    }
    for (; s < r1; s++){
      int sn = csr_src[s];
      if (nmask[sn] > 0.f){
        float a = lrelu(alS[sn*4 + h] + ald_i + ALE[(size_t)csr_eid[s]*4 + h]);
        float4 v = xs4[(size_t)sn*32 + cidx];
        float mn = fmaxf(m, a); float pm = expf(m - mn); float pa = expf(a - mn);
        den = den*pm + pa;
        acc.x = acc.x*pm + pa*v.x; acc.y = acc.y*pm + pa*v.y;
        acc.z = acc.z*pm + pa*v.z; acc.w = acc.w*pm + pa*v.w;
        m = mn;
      }
    }
  }
  den = fmaxf(den, 1e-16f);
  float rd = 1.f/den;
  int cb = cidx << 2;
  float4 o;
  o.x = fmaxf(acc.x*rd + g_b[cb+0], 0.f);
  o.y = fmaxf(acc.y*rd + g_b[cb+1], 0.f);
  o.z = fmaxf(acc.z*rd + g_b[cb+2], 0.f);
  o.w = fmaxf(acc.w*rd + g_b[cb+3], 0.f);
  *(float4*)&OUT[((size_t)i << 7) + cb] = o;
}

// ---------------- final MLP ----------------
__global__ void __launch_bounds__(128) k_mlp(const float* x1g, const float* x2g, const float* x3g,
    const float* l1w, const float* l1b, const float* l2w, const float* l2b,
    const float* l3w, const float* l3b, float* out){
  __shared__ float hh[128];
  __shared__ float h2[128];
  __shared__ float h3[64];
  int b = blockIdx.x, t = threadIdx.x;
  hh[t] = x1g[b*128 + t] + x2g[b*128 + t] + x3g[b*128 + t];
  __syncthreads();
  float a = l1b[t];
  for (int k = 0; k < 128; k++) a += hh[k] * l1w[k*128 + t];
  h2[t] = fmaxf(a, 0.f);
  __syncthreads();
  if (t < 64){
    float a2 = l2b[t];
    for (int k = 0; k < 128; k++) a2 += h2[k] * l2w[k*64 + t];
    h3[t] = fmaxf(a2, 0.f);
  }
  __syncthreads();
  if (t == 0){
    float z = l3b[0];
    for (int k = 0; k < 64; k++) z += h3[k] * l3w[k];
    out[b] = 1.f/(1.f + expf(-z));
  }
}

// ---------------- launch ----------------
extern "C" void kernel_launch(void* const* d_in, const int* in_sizes, int n_in,
                              void* d_out, int out_size, void* d_ws, size_t ws_size,
                              hipStream_t stream){
  const float* x       = (const float*)d_in[0];
  const int*   ei      = (const int*)d_in[1];
  const float* ea      = (const float*)d_in[2];
  const float* c1_wl   = (const float*)d_in[3];
  const float* c1_bl   = (const float*)d_in[4];
  const float* c1_wr   = (const float*)d_in[5];
  const float* p1_w    = (const float*)d_in[6];
  const float* c2_wl   = (const float*)d_in[7];
  const float* c2_bl   = (const float*)d_in[8];
  const float* c2_wr   = (const float*)d_in[9];
  const float* p2_wrel = (const float*)d_in[10];
  const float* p2_brel = (const float*)d_in[11];
  const float* p2_wroot= (const float*)d_in[12];
  const float* g_w     = (const float*)d_in[13];
  const float* g_as    = (const float*)d_in[14];
  const float* g_ad    = (const float*)d_in[15];
  const float* g_we    = (const float*)d_in[16];
  const float* g_ae    = (const float*)d_in[17];
  const float* g_b     = (const float*)d_in[18];
  const float* p3_wrel = (const float*)d_in[19];
  const float* p3_brel = (const float*)d_in[20];
  const float* p3_wroot= (const float*)d_in[21];
  const float* l1_w    = (const float*)d_in[22];
  const float* l1_b    = (const float*)d_in[23];
  const float* l2_w    = (const float*)d_in[24];
  const float* l2_b    = (const float*)d_in[25];
  const float* l3_w    = (const float*)d_in[26];
  const float* l3_b    = (const float*)d_in[27];
  float* out = (float*)d_out;
  (void)in_sizes; (void)n_in; (void)out_size;

  // Workspace layout (f32, ~137 MB)
  char* w = (char*)d_ws;
  size_t off = 0;
  float* AGG  = (float*)(w + off); off += (size_t)NBV*128*4;
  float* F1   = (float*)(w + off); off += (size_t)NBV*128*4;
  float* F2   = (float*)(w + off); off += (size_t)NBV*128*4;
  float* ALE  = (float*)(w + off); off += (size_t)EV*4*4;
  float* sA   = (float*)(w + off); off += (size_t)NBV*4;
  float* sel  = (float*)(w + off); off += (size_t)NBV*4;
  float* qv   = (float*)(w + off); off += (size_t)NBV*4;
  float* rv   = (float*)(w + off); off += (size_t)NBV*4;
  float* nmask= (float*)(w + off); off += (size_t)NBV*4;
  float* alS  = (float*)(w + off); off += (size_t)NBV*4*4;
  float* alD  = (float*)(w + off); off += (size_t)NBV*4*4;
  float* x1g  = (float*)(w + off); off += (size_t)BV*128*4;
  float* x2g  = (float*)(w + off); off += (size_t)BV*128*4;
  float* x3g  = (float*)(w + off); off += (size_t)BV*128*4;
  float* sml  = (float*)(w + off); off += 64*4;      // [0]=invnorm [8..15]=easum [16..19]=alse [20..47]=ve
  float* eprt = (float*)(w + off); off += 2048*4;
  float* gprt = (float*)(w + off); off += (size_t)1024*128*4;
  int* csr_src = (int*)(w + off); off += (size_t)EV*4;
  int* csr_eid = (int*)(w + off); off += (size_t)EV*4;
  int* rp      = (int*)(w + off); off += (size_t)(NBV+64)*4;
  int* dcnt    = (int*)(w + off); off += (size_t)(NBV+64)*4;
  int* bsum    = (int*)(w + off); off += 1024;
  size_t needed = off;

  float sentinel = (ws_size >= needed) ? 0.125f : 0.875f;
  k_sentinel<<<1, 128, 0, stream>>>(out, sentinel);

  const int* srcA = ei;
  const int* dstA = ei + EV;

  // ---- setup ----
  k_fill1<<<NBV/256, 256, 0, stream>>>(nmask, NBV);
  k_zero_i<<<(NBV+256)/256, 256, 0, stream>>>(dcnt, NBV+1);
  k_hist<<<EV/256, 256, 0, stream>>>(dstA, dcnt);
  k_scan1<<<256, 256, 0, stream>>>(dcnt, rp, bsum);
  k_scan2<<<1, 256, 0, stream>>>(bsum);
  k_scan3<<<256, 256, 0, stream>>>(rp, dcnt, bsum);
  k_zero_i<<<(NBV+256)/256, 256, 0, stream>>>(dcnt, NBV+1);
  k_scatter<<<EV/256, 256, 0, stream>>>(srcA, dstA, rp, dcnt, csr_src, csr_eid);
  k_ve<<<1, 32, 0, stream>>>(g_we, g_ae, sml+20);
  k_ale<<<EV/256, 256, 0, stream>>>(ea, sml+20, ALE);

  // ---- block 1: SAGE -> TopK(410) -> gap  (x -> F1) ----
  k_invnorm<<<1, 128, 0, stream>>>(p1_w, sml);
  k_sage_agg<<<(NBV*32)/256, 256, 0, stream>>>(x, nmask, rp, csr_src, AGG, 0);
  k_gemm<<<NBV/128, 512, 0, stream>>>(AGG, x, c1_wl, c1_wr, c1_bl, F1, 1, 1, 1);
  k_score1<<<(NBV*32)/256, 256, 0, stream>>>(F1, p1_w, sml, sA);
  k_pool<<<BV, 512, 0, stream>>>(sA, nmask, sel, K1V);
  k_scale_part<<<BV*8, 128, 0, stream>>>(F1, sel, gprt);
  k_gap_final<<<BV, 128, 0, stream>>>(gprt, x1g, 1.f/(float)K1V);

  // ---- block 2: SAGE -> SAGPool(205) -> gap  (F1 -> F2) ----
  k_sage_agg<<<(NBV*32)/256, 256, 0, stream>>>(F1, nmask, rp, csr_src, AGG, 1);
  k_gemm<<<NBV/128, 512, 0, stream>>>(AGG, F1, c2_wl, c2_wr, c2_bl, F2, 1, 1, 1);
  k_qr<<<(NBV*32)/256, 256, 0, stream>>>(F2, p2_wrel, p2_wroot, qv, rv);
  k_gconv<<<NBV/256, 256, 0, stream>>>(qv, rv, nmask, rp, csr_src, p2_brel, sA);
  k_pool<<<BV, 512, 0, stream>>>(sA, nmask, sel, K2V);
  k_scale_part<<<BV*8, 128, 0, stream>>>(F2, sel, gprt);
  k_gap_final<<<BV, 128, 0, stream>>>(gprt, x2g, 1.f/(float)K2V);

  // ---- block 3: GAT -> SAGPool(103) -> gap  (F2 -> xs=AGG -> F1) ----
  k_gemm<<<NBV/128, 512, 0, stream>>>(F2, F2, g_w, g_w, g_b, AGG, 0, 0, 0);  // xs = F2 @ g_w
  k_heads<<<(NBV*4)/256, 256, 0, stream>>>(AGG, g_as, g_ad, alS, alD);
  k_ea_part<<<256, 256, 0, stream>>>(ea, srcA, dstA, nmask, eprt);
  k_ea_final<<<1, 64, 0, stream>>>(eprt, sml+8);
  k_alse<<<1, 64, 0, stream>>>(sml+8, sml+20, sml+16);
  k_gat<<<(NBV*32)/256, 256, 0, stream>>>(AGG, alS, alD, ALE, nmask, rp, csr_src, csr_eid, sml+16, g_b, F1);
  k_qr<<<(NBV*32)/256, 256, 0, stream>>>(F1, p3_wrel, p3_wroot, qv, rv);
  k_gconv<<<NBV/256, 256, 0, stream>>>(qv, rv, nmask, rp, csr_src, p3_brel, sA);
  k_pool<<<BV, 512, 0, stream>>>(sA, nmask, sel, K3V);
  k_scale_part<<<BV*8, 128, 0, stream>>>(F1, sel, gprt);
  k_gap_final<<<BV, 128, 0, stream>>>(gprt, x3g, 1.f/(float)K3V);

  // ---- readout MLP ----
  k_mlp<<<BV, 128, 0, stream>>>(x1g, x2g, x3g, l1_w, l1_b, l2_w, l2_b, l3_w, l3_b, out);
}

// Round 4
// 686.108 us; speedup vs baseline: 5.8120x; 2.4599x over previous
//
#include <hip/hip_runtime.h>
#include <math.h>

#define NBV 65536
#define EV  1048576
#define BV  128
#define K1V 410
#define K2V 205
#define K3V 103
#define NEG_BIG (-1.0e38f)

__device__ __forceinline__ float lrelu(float x){ return x > 0.f ? x : 0.2f*x; }

// ---------------- diagnostics sentinel ----------------
__global__ void k_sentinel(float* out, float v){
  int i = threadIdx.x;
  if (i < 128) out[i] = v;
}

// ---------------- utility ----------------
__global__ void k_fill1(float* p, int n){
  int i = blockIdx.x*blockDim.x + threadIdx.x;
  if (i < n) p[i] = 1.f;
}

__global__ void k_zero_i(int* p, int n){
  int i = blockIdx.x*blockDim.x + threadIdx.x;
  if (i < n) p[i] = 0;
}

// ---------------- CSR build (int atomics only) ----------------
__global__ void k_hist(const int* dst, int* dcnt){
  int e = blockIdx.x*blockDim.x + threadIdx.x;
  if (e < EV) atomicAdd(&dcnt[dst[e]], 1);
}

__global__ void k_scan1(const int* dcnt, int* rp, int* bsum){
  __shared__ int sc[256];
  int t = threadIdx.x, i = blockIdx.x*256 + t;
  int v = dcnt[i];
  sc[t] = v; __syncthreads();
  for (int o = 1; o < 256; o <<= 1){
    int x = (t >= o) ? sc[t-o] : 0;
    __syncthreads();
    sc[t] += x;
    __syncthreads();
  }
  rp[i] = sc[t];
  if (t == 255) bsum[blockIdx.x] = sc[t];
}

__global__ void k_scan2(int* bsum){
  __shared__ int sc[256];
  int t = threadIdx.x;
  int v = bsum[t];
  sc[t] = v; __syncthreads();
  for (int o = 1; o < 256; o <<= 1){
    int x = (t >= o) ? sc[t-o] : 0;
    __syncthreads();
    sc[t] += x;
    __syncthreads();
  }
  bsum[t] = sc[t] - v;
}

__global__ void k_scan3(int* rp, const int* dcnt, const int* bsum){
  int t = threadIdx.x, i = blockIdx.x*256 + t;
  rp[i] = rp[i] - dcnt[i] + bsum[blockIdx.x];
  if (i == 0) rp[NBV] = EV;
}

__global__ void k_scatter(const int* src, const int* dst, const int* rp, int* fill,
                          int* csr_src, int* csr_eid){
  int e = blockIdx.x*blockDim.x + threadIdx.x;
  if (e < EV){
    int d = dst[e];
    int pos = atomicAdd(&fill[d], 1);
    int slot = rp[d] + pos;
    csr_src[slot] = src[e];
    csr_eid[slot] = e;
  }
}

// ---------------- small precomputes ----------------
__global__ void k_invnorm(const float* wv, float* outv){
  __shared__ float sc[128];
  int t = threadIdx.x;
  float v = wv[t];
  sc[t] = v*v; __syncthreads();
  for (int o = 64; o > 0; o >>= 1){ if (t < o) sc[t] += sc[t+o]; __syncthreads(); }
  if (t == 0) outv[0] = 1.f / sqrtf(sc[0]);
}

__global__ void k_ve(const float* g_we, const float* g_ae, float* ve){
  int t = threadIdx.x;
  if (t < 28){
    int ed = t >> 2, h = t & 3;
    float a = 0.f;
    for (int c = 0; c < 32; c++) a += g_we[ed*128 + h*32 + c] * g_ae[h*32 + c];
    ve[t] = a;
  }
}

__global__ void k_ale(const float* ea, const float* ve, float* ALE){
  int e = blockIdx.x*blockDim.x + threadIdx.x;
  if (e < EV){
    float a0=0.f,a1=0.f,a2=0.f,a3=0.f;
    for (int ed = 0; ed < 7; ed++){
      float x = ea[e*7 + ed];
      a0 += x*ve[ed*4+0]; a1 += x*ve[ed*4+1]; a2 += x*ve[ed*4+2]; a3 += x*ve[ed*4+3];
    }
    float4 o; o.x=a0; o.y=a1; o.z=a2; o.w=a3;
    *(float4*)&ALE[(size_t)e*4] = o;
  }
}

// ---------------- SAGE mean aggregation (XCD-swizzled, 4-deep gather) ----------------
__global__ void __launch_bounds__(256) k_sage_agg(const float* X, const float* nmask,
    const int* rp, const int* csr_src, float* AGG, int masked){
  int g = blockIdx.x & 127;
  int blk = blockIdx.x >> 7;
  int i = g*512 + blk*8 + (threadIdx.x >> 5);
  int c4 = threadIdx.x & 31;
  float ax=0.f,ay=0.f,az=0.f,aw=0.f,cnt=0.f;
  if (!masked || nmask[i] > 0.f){
    int r0 = rp[i], r1 = rp[i+1];
    int s = r0;
    for (; s + 4 <= r1; s += 4){
      int sn0 = csr_src[s+0], sn1 = csr_src[s+1], sn2 = csr_src[s+2], sn3 = csr_src[s+3];
      float4 v0 = *(const float4*)&X[((size_t)sn0 << 7) + (c4 << 2)];
      float4 v1 = *(const float4*)&X[((size_t)sn1 << 7) + (c4 << 2)];
      float4 v2 = *(const float4*)&X[((size_t)sn2 << 7) + (c4 << 2)];
      float4 v3 = *(const float4*)&X[((size_t)sn3 << 7) + (c4 << 2)];
      float nm0 = masked ? nmask[sn0] : 1.f;
      float nm1 = masked ? nmask[sn1] : 1.f;
      float nm2 = masked ? nmask[sn2] : 1.f;
      float nm3 = masked ? nmask[sn3] : 1.f;
      if (nm0 > 0.f){ ax += v0.x; ay += v0.y; az += v0.z; aw += v0.w; cnt += 1.f; }
      if (nm1 > 0.f){ ax += v1.x; ay += v1.y; az += v1.z; aw += v1.w; cnt += 1.f; }
      if (nm2 > 0.f){ ax += v2.x; ay += v2.y; az += v2.z; aw += v2.w; cnt += 1.f; }
      if (nm3 > 0.f){ ax += v3.x; ay += v3.y; az += v3.z; aw += v3.w; cnt += 1.f; }
    }
    for (; s < r1; s++){
      int sn = csr_src[s];
      float nm = masked ? nmask[sn] : 1.f;
      if (nm > 0.f){
        const float4 v = *(const float4*)&X[((size_t)sn << 7) + (c4 << 2)];
        ax += v.x; ay += v.y; az += v.z; aw += v.w; cnt += 1.f;
      }
    }
  }
  float inv = 1.f / fmaxf(cnt, 1.f);
  float4 o; o.x = ax*inv; o.y = ay*inv; o.z = az*inv; o.w = aw*inv;
  *(float4*)&AGG[((size_t)i << 7) + (c4 << 2)] = o;
}

// ---------------- dual GEMM f32, W-resident, register-parked A pipeline ----------------
// PROVEN baseline: 66 us/dispatch, VGPR 64, zero scratch (R0 counters).
// LESSON (r13-r15): do NOT stream W in K-chunks with a 2-deep dbuf here — that
// schedule's true VGPR need exceeds 128 (compiler pre-schedules 48 ds_reads),
// so it spills at ANY allocator budget: arg2=8 ->32 VGPR (4.9GB scratch),
// arg2=6 ->40, none ->128 (2.3GB scratch, 520us). Also: on this toolchain
// __launch_bounds__ arg2 is CUDA-style min-BLOCKS-per-CU (measured exactly),
// so never pass arg2 with 512-thread blocks unless you want <=64 VGPR.
__global__ void __launch_bounds__(512) k_gemm(const float* A1, const float* A2,
    const float* W1, const float* W2, const float* bias,
    float* OUT, int has2, int relu, int hasb){
  __shared__ float ws[128][128];
  __shared__ float as[16][136];
  int t = threadIdx.x;
  int n0 = blockIdx.x * 128;
  int rowg = t >> 5;
  int colg = t & 31;
  int rb = rowg * 8;
  int jb = colg * 4;
  int an = t >> 2;              // A-stage row 0..127
  int ak = (t & 3) << 2;        // A-stage k offset {0,4,8,12}
  float acc[8][4];
  for (int r = 0; r < 8; r++)
    for (int j = 0; j < 4; j++) acc[r][j] = 0.f;
  int nmat = has2 ? 2 : 1;
  for (int m = 0; m < nmat; m++){
    const float* A = (m == 0) ? A1 : A2;
    const float* W = (m == 0) ? W1 : W2;
    __syncthreads();   // prior readers of ws/as done (no-op cost at m==0)
    for (int ii = 0; ii < 8; ii++){
      int idx4 = t + 512*ii;
      int kk = idx4 >> 5;
      int jj = (idx4 & 31) << 2;
      *(float4*)&ws[kk][jj] = *(const float4*)&W[kk*128 + jj];
    }
    float4 rA = *(const float4*)&A[((size_t)(n0+an) << 7) + ak];   // chunk 0
    for (int c = 0; c < 8; c++){
      if (c > 0) __syncthreads();        // prior compute done reading as
      as[ak+0][an] = rA.x;
      as[ak+1][an] = rA.y;
      as[ak+2][an] = rA.z;
      as[ak+3][an] = rA.w;
      __syncthreads();                   // as (and ws on c==0) visible
      if (c+1 < 8)
        rA = *(const float4*)&A[((size_t)(n0+an) << 7) + (c+1)*16 + ak];  // prefetch
      int kb = c*16;
      for (int kk = 0; kk < 16; kk++){
        float4 wv = *(const float4*)&ws[kb+kk][jb];
        float4 aL = *(const float4*)&as[kk][rb];
        float4 aH = *(const float4*)&as[kk][rb+4];
        float a0=aL.x,a1=aL.y,a2=aL.z,a3=aL.w,a4=aH.x,a5=aH.y,a6=aH.z,a7=aH.w;
        acc[0][0]+=a0*wv.x; acc[0][1]+=a0*wv.y; acc[0][2]+=a0*wv.z; acc[0][3]+=a0*wv.w;
        acc[1][0]+=a1*wv.x; acc[1][1]+=a1*wv.y; acc[1][2]+=a1*wv.z; acc[1][3]+=a1*wv.w;
        acc[2][0]+=a2*wv.x; acc[2][1]+=a2*wv.y; acc[2][2]+=a2*wv.z; acc[2][3]+=a2*wv.w;
        acc[3][0]+=a3*wv.x; acc[3][1]+=a3*wv.y; acc[3][2]+=a3*wv.z; acc[3][3]+=a3*wv.w;
        acc[4][0]+=a4*wv.x; acc[4][1]+=a4*wv.y; acc[4][2]+=a4*wv.z; acc[4][3]+=a4*wv.w;
        acc[5][0]+=a5*wv.x; acc[5][1]+=a5*wv.y; acc[5][2]+=a5*wv.z; acc[5][3]+=a5*wv.w;
        acc[6][0]+=a6*wv.x; acc[6][1]+=a6*wv.y; acc[6][2]+=a6*wv.z; acc[6][3]+=a6*wv.w;
        acc[7][0]+=a7*wv.x; acc[7][1]+=a7*wv.y; acc[7][2]+=a7*wv.z; acc[7][3]+=a7*wv.w;
      }
    }
  }
  float bj0=0.f,bj1=0.f,bj2=0.f,bj3=0.f;
  if (hasb){
    bj0 = bias[jb+0]; bj1 = bias[jb+1]; bj2 = bias[jb+2]; bj3 = bias[jb+3];
  }
  for (int r = 0; r < 8; r++){
    float4 o;
    o.x = acc[r][0]+bj0; o.y = acc[r][1]+bj1; o.z = acc[r][2]+bj2; o.w = acc[r][3]+bj3;
    if (relu){
      o.x = fmaxf(o.x,0.f); o.y = fmaxf(o.y,0.f); o.z = fmaxf(o.z,0.f); o.w = fmaxf(o.w,0.f);
    }
    *(float4*)&OUT[((size_t)(n0+rb+r) << 7) + jb] = o;
  }
}

// ---------------- scores (32 lanes/node, shfl reduce) ----------------
__global__ void __launch_bounds__(256) k_score1(const float* X, const float* pw, const float* invn, float* s){
  int gid = blockIdx.x*256 + threadIdx.x;
  int i = gid >> 5, c4 = gid & 31;
  float4 v = *(const float4*)&X[((size_t)i << 7) + (c4 << 2)];
  float4 wv = *(const float4*)&pw[c4 << 2];
  float a = v.x*wv.x + v.y*wv.y + v.z*wv.z + v.w*wv.w;
  for (int o = 16; o > 0; o >>= 1) a += __shfl_down(a, o, 32);
  if (c4 == 0) s[i] = tanhf(a * invn[0]);
}

__global__ void __launch_bounds__(256) k_qr(const float* X, const float* wrel, const float* wroot,
                                            float* q, float* r){
  int gid = blockIdx.x*256 + threadIdx.x;
  int i = gid >> 5, c4 = gid & 31;
  float4 v = *(const float4*)&X[((size_t)i << 7) + (c4 << 2)];
  float4 wa = *(const float4*)&wrel[c4 << 2];
  float4 wb = *(const float4*)&wroot[c4 << 2];
  float aq = v.x*wa.x + v.y*wa.y + v.z*wa.z + v.w*wa.w;
  float ar = v.x*wb.x + v.y*wb.y + v.z*wb.z + v.w*wb.w;
  for (int o = 16; o > 0; o >>= 1){
    aq += __shfl_down(aq, o, 32);
    ar += __shfl_down(ar, o, 32);
  }
  if (c4 == 0){ q[i] = aq; r[i] = ar; }
}

__global__ void k_gconv(const float* q, const float* r, const float* nmask,
    const int* rp, const int* csr_src, const float* brel, float* s){
  int i = blockIdx.x*blockDim.x + threadIdx.x;
  if (i >= NBV) return;
  float acc = 0.f;
  if (nmask[i] > 0.f){
    int r0 = rp[i], r1 = rp[i+1];
    int t2 = r0;
    for (; t2 + 4 <= r1; t2 += 4){
      int sn0 = csr_src[t2+0], sn1 = csr_src[t2+1], sn2 = csr_src[t2+2], sn3 = csr_src[t2+3];
      float nm0 = nmask[sn0], nm1 = nmask[sn1], nm2 = nmask[sn2], nm3 = nmask[sn3];
      float q0 = q[sn0], q1 = q[sn1], q2 = q[sn2], q3 = q[sn3];
      if (nm0 > 0.f) acc += q0;
      if (nm1 > 0.f) acc += q1;
      if (nm2 > 0.f) acc += q2;
      if (nm3 > 0.f) acc += q3;
    }
    for (; t2 < r1; t2++){
      int sn = csr_src[t2];
      if (nmask[sn] > 0.f) acc += q[sn];
    }
  }
  s[i] = tanhf(acc + brel[0] + r[i]);
}

// ---------------- top-k pool (stable tie-break == jax.lax.top_k) ----------------
__global__ void __launch_bounds__(512) k_pool(const float* s, float* nmask, float* sel, int K){
  __shared__ float sc[512];
  int b = blockIdx.x, t = threadIdx.x;
  int i = b*512 + t;
  float nm = nmask[i];
  float sv = s[i];
  float ms = (nm > 0.f) ? sv : NEG_BIG;
  sc[t] = ms;
  __syncthreads();
  int rank = 0;
  for (int j = 0; j < 512; j++){
    float o = sc[j];
    rank += ((o > ms) || (o == ms && j < t)) ? 1 : 0;
  }
  bool selb = rank < K;
  nmask[i] = selb ? 1.f : 0.f;
  sel[i] = selb ? sv : 0.f;
}

// scale kept rows by score (in place) + gap partials — no atomics.
__global__ void __launch_bounds__(128) k_scale_part(float* X, const float* sel, float* part){
  int b = blockIdx.x >> 3, q = blockIdx.x & 7, c = threadIdx.x;
  float acc = 0.f;
  for (int n = q*64; n < q*64 + 64; n++){
    int i = b*512 + n;
    float v = X[((size_t)i << 7) + c] * sel[i];
    X[((size_t)i << 7) + c] = v;
    acc += v;
  }
  part[(size_t)blockIdx.x*128 + c] = acc;
}

__global__ void __launch_bounds__(128) k_gap_final(const float* part, float* gap, float invK){
  int b = blockIdx.x, c = threadIdx.x;
  float s = 0.f;
  for (int q = 0; q < 8; q++) s += part[(size_t)(b*8+q)*128 + c];
  gap[b*128 + c] = s * invK;
}

// ---------------- GAT pieces ----------------
__global__ void k_heads(const float* xs, const float* a_s, const float* a_d,
                        float* alS, float* alD){
  int gid = blockIdx.x*blockDim.x + threadIdx.x;
  int i = gid >> 2, h = gid & 3;
  if (i >= NBV) return;
  const float4* xr = (const float4*)&xs[((size_t)i << 7) + h*32];
  const float4* wa = (const float4*)&a_s[h*32];
  const float4* wd = (const float4*)&a_d[h*32];
  float as_ = 0.f, ad_ = 0.f;
  for (int c4 = 0; c4 < 8; c4++){
    float4 v = xr[c4]; float4 A = wa[c4]; float4 D = wd[c4];
    as_ += v.x*A.x + v.y*A.y + v.z*A.z + v.w*A.w;
    ad_ += v.x*D.x + v.y*D.y + v.z*D.z + v.w*D.w;
  }
  alS[gid] = as_; alD[gid] = ad_;
}

// edge-attr masked mean: per-block partials (no atomics)
__global__ void __launch_bounds__(256) k_ea_part(const float* ea, const int* srcA, const int* dstA,
    const float* nmask, float* part){
  float p[8] = {0.f,0.f,0.f,0.f,0.f,0.f,0.f,0.f};
  for (int e = blockIdx.x*256 + threadIdx.x; e < EV; e += 256*256){
    if (nmask[srcA[e]] > 0.f && nmask[dstA[e]] > 0.f){
      for (int d = 0; d < 7; d++) p[d] += ea[e*7 + d];
      p[7] += 1.f;
    }
  }
  __shared__ float red[256];
  for (int comp = 0; comp < 8; comp++){
    red[threadIdx.x] = p[comp]; __syncthreads();
    for (int o = 128; o > 0; o >>= 1){ if (threadIdx.x < o) red[threadIdx.x] += red[threadIdx.x + o]; __syncthreads(); }
    if (threadIdx.x == 0) part[blockIdx.x*8 + comp] = red[0];
    __syncthreads();
  }
}

__global__ void k_ea_final(const float* part, float* easum){
  int h = threadIdx.x;
  if (h < 8){
    float s = 0.f;
    for (int b = 0; b < 256; b++) s += part[b*8 + h];
    easum[h] = s;
  }
}

__global__ void k_alse(const float* easum, const float* ve, float* alse){
  if (threadIdx.x == 0 && blockIdx.x == 0){
    float cnt = fmaxf(easum[7], 1.f);
    for (int h = 0; h < 4; h++){
      float s = 0.f;
      for (int ed = 0; ed < 7; ed++) s += (easum[ed]/cnt) * ve[ed*4 + h];
      alse[h] = s;
    }
  }
}

// GAT: 32 threads/node, XCD-swizzled, 4-deep gathers + in-order online softmax.
__global__ void __launch_bounds__(256) k_gat(const float* xs, const float* alS, const float* alD,
    const float* ALE, const float* nmask, const int* rp, const int* csr_src,
    const int* csr_eid, const float* alse, const float* g_b, float* OUT){
  int g = blockIdx.x & 127;
  int blk = blockIdx.x >> 7;
  int i = g*512 + blk*8 + (threadIdx.x >> 5);
  int lane = threadIdx.x & 31;
  int h = lane >> 3;
  int cidx = h*8 + (lane & 7);
  float nmi = nmask[i];
  const float4* xs4 = (const float4*)xs;
  float m = 0.f, den = 0.f;
  float4 acc; acc.x=0.f; acc.y=0.f; acc.z=0.f; acc.w=0.f;
  if (nmi > 0.f){
    float ald_i = alD[i*4 + h];
    m = lrelu(alS[i*4 + h] + ald_i + alse[h]);   // aself
    den = 1.f;
    acc = xs4[(size_t)i*32 + cidx];
    int r0 = rp[i], r1 = rp[i+1];
    int s = r0;
    for (; s + 4 <= r1; s += 4){
      int sn0 = csr_src[s+0], sn1 = csr_src[s+1], sn2 = csr_src[s+2], sn3 = csr_src[s+3];
      int e0 = csr_eid[s+0], e1 = csr_eid[s+1], e2 = csr_eid[s+2], e3 = csr_eid[s+3];
      float nm0 = nmask[sn0], nm1 = nmask[sn1], nm2 = nmask[sn2], nm3 = nmask[sn3];
      float al0 = alS[sn0*4 + h], al1 = alS[sn1*4 + h], al2 = alS[sn2*4 + h], al3 = alS[sn3*4 + h];
      float ae0 = ALE[(size_t)e0*4 + h], ae1 = ALE[(size_t)e1*4 + h];
      float ae2 = ALE[(size_t)e2*4 + h], ae3 = ALE[(size_t)e3*4 + h];
      float4 v0 = xs4[(size_t)sn0*32 + cidx];
      float4 v1 = xs4[(size_t)sn1*32 + cidx];
      float4 v2 = xs4[(size_t)sn2*32 + cidx];
      float4 v3 = xs4[(size_t)sn3*32 + cidx];
      if (nm0 > 0.f){
        float a = lrelu(al0 + ald_i + ae0);
        float mn = fmaxf(m, a); float pm = expf(m - mn); float pa = expf(a - mn);
        den = den*pm + pa;
        acc.x = acc.x*pm + pa*v0.x; acc.y = acc.y*pm + pa*v0.y;
        acc.z = acc.z*pm + pa*v0.z; acc.w = acc.w*pm + pa*v0.w;
        m = mn;
      }
      if (nm1 > 0.f){
        float a = lrelu(al1 + ald_i + ae1);
        float mn = fmaxf(m, a); float pm = expf(m - mn); float pa = expf(a - mn);
        den = den*pm + pa;
        acc.x = acc.x*pm + pa*v1.x; acc.y = acc.y*pm + pa*v1.y;
        acc.z = acc.z*pm + pa*v1.z; acc.w = acc.w*pm + pa*v1.w;
        m = mn;
      }
      if (nm2 > 0.f){
        float a = lrelu(al2 + ald_i + ae2);
        float mn = fmaxf(m, a); float pm = expf(m - mn); float pa = expf(a - mn);
        den = den*pm + pa;
        acc.x = acc.x*pm + pa*v2.x; acc.y = acc.y*pm + pa*v2.y;
        acc.z = acc.z*pm + pa*v2.z; acc.w = acc.w*pm + pa*v2.w;
        m = mn;
      }
      if (nm3 > 0.f){
        float a = lrelu(al3 + ald_i + ae3);
        float mn = fmaxf(m, a); float pm = expf(m - mn); float pa = expf(a - mn);
        den = den*pm + pa;
        acc.x = acc.x*pm + pa*v3.x; acc.y = acc.y*pm + pa*v3.y;
        acc.z = acc.z*pm + pa*v3.z; acc.w = acc.w*pm + pa*v3.w;
        m = mn;
      }
    }
    for (; s < r1; s++){
      int sn = csr_src[s];
      if (nmask[sn] > 0.f){
        float a = lrelu(alS[sn*4 + h] + ald_i + ALE[(size_t)csr_eid[s]*4 + h]);
        float4 v = xs4[(size_t)sn*32 + cidx];
        float mn = fmaxf(m, a); float pm = expf(m - mn); float pa = expf(a - mn);
        den = den*pm + pa;
        acc.x = acc.x*pm + pa*v.x; acc.y = acc.y*pm + pa*v.y;
        acc.z = acc.z*pm + pa*v.z; acc.w = acc.w*pm + pa*v.w;
        m = mn;
      }
    }
  }
  den = fmaxf(den, 1e-16f);
  float rd = 1.f/den;
  int cb = cidx << 2;
  float4 o;
  o.x = fmaxf(acc.x*rd + g_b[cb+0], 0.f);
  o.y = fmaxf(acc.y*rd + g_b[cb+1], 0.f);
  o.z = fmaxf(acc.z*rd + g_b[cb+2], 0.f);
  o.w = fmaxf(acc.w*rd + g_b[cb+3], 0.f);
  *(float4*)&OUT[((size_t)i << 7) + cb] = o;
}

// ---------------- final MLP ----------------
__global__ void __launch_bounds__(128) k_mlp(const float* x1g, const float* x2g, const float* x3g,
    const float* l1w, const float* l1b, const float* l2w, const float* l2b,
    const float* l3w, const float* l3b, float* out){
  __shared__ float hh[128];
  __shared__ float h2[128];
  __shared__ float h3[64];
  int b = blockIdx.x, t = threadIdx.x;
  hh[t] = x1g[b*128 + t] + x2g[b*128 + t] + x3g[b*128 + t];
  __syncthreads();
  float a = l1b[t];
  for (int k = 0; k < 128; k++) a += hh[k] * l1w[k*128 + t];
  h2[t] = fmaxf(a, 0.f);
  __syncthreads();
  if (t < 64){
    float a2 = l2b[t];
    for (int k = 0; k < 128; k++) a2 += h2[k] * l2w[k*64 + t];
    h3[t] = fmaxf(a2, 0.f);
  }
  __syncthreads();
  if (t == 0){
    float z = l3b[0];
    for (int k = 0; k < 64; k++) z += h3[k] * l3w[k];
    out[b] = 1.f/(1.f + expf(-z));
  }
}

// ---------------- launch ----------------
extern "C" void kernel_launch(void* const* d_in, const int* in_sizes, int n_in,
                              void* d_out, int out_size, void* d_ws, size_t ws_size,
                              hipStream_t stream){
  const float* x       = (const float*)d_in[0];
  const int*   ei      = (const int*)d_in[1];
  const float* ea      = (const float*)d_in[2];
  const float* c1_wl   = (const float*)d_in[3];
  const float* c1_bl   = (const float*)d_in[4];
  const float* c1_wr   = (const float*)d_in[5];
  const float* p1_w    = (const float*)d_in[6];
  const float* c2_wl   = (const float*)d_in[7];
  const float* c2_bl   = (const float*)d_in[8];
  const float* c2_wr   = (const float*)d_in[9];
  const float* p2_wrel = (const float*)d_in[10];
  const float* p2_brel = (const float*)d_in[11];
  const float* p2_wroot= (const float*)d_in[12];
  const float* g_w     = (const float*)d_in[13];
  const float* g_as    = (const float*)d_in[14];
  const float* g_ad    = (const float*)d_in[15];
  const float* g_we    = (const float*)d_in[16];
  const float* g_ae    = (const float*)d_in[17];
  const float* g_b     = (const float*)d_in[18];
  const float* p3_wrel = (const float*)d_in[19];
  const float* p3_brel = (const float*)d_in[20];
  const float* p3_wroot= (const float*)d_in[21];
  const float* l1_w    = (const float*)d_in[22];
  const float* l1_b    = (const float*)d_in[23];
  const float* l2_w    = (const float*)d_in[24];
  const float* l2_b    = (const float*)d_in[25];
  const float* l3_w    = (const float*)d_in[26];
  const float* l3_b    = (const float*)d_in[27];
  float* out = (float*)d_out;
  (void)in_sizes; (void)n_in; (void)out_size;

  // Workspace layout (f32, ~137 MB)
  char* w = (char*)d_ws;
  size_t off = 0;
  float* AGG  = (float*)(w + off); off += (size_t)NBV*128*4;
  float* F1   = (float*)(w + off); off += (size_t)NBV*128*4;
  float* F2   = (float*)(w + off); off += (size_t)NBV*128*4;
  float* ALE  = (float*)(w + off); off += (size_t)EV*4*4;
  float* sA   = (float*)(w + off); off += (size_t)NBV*4;
  float* sel  = (float*)(w + off); off += (size_t)NBV*4;
  float* qv   = (float*)(w + off); off += (size_t)NBV*4;
  float* rv   = (float*)(w + off); off += (size_t)NBV*4;
  float* nmask= (float*)(w + off); off += (size_t)NBV*4;
  float* alS  = (float*)(w + off); off += (size_t)NBV*4*4;
  float* alD  = (float*)(w + off); off += (size_t)NBV*4*4;
  float* x1g  = (float*)(w + off); off += (size_t)BV*128*4;
  float* x2g  = (float*)(w + off); off += (size_t)BV*128*4;
  float* x3g  = (float*)(w + off); off += (size_t)BV*128*4;
  float* sml  = (float*)(w + off); off += 64*4;      // [0]=invnorm [8..15]=easum [16..19]=alse [20..47]=ve
  float* eprt = (float*)(w + off); off += 2048*4;
  float* gprt = (float*)(w + off); off += (size_t)1024*128*4;
  int* csr_src = (int*)(w + off); off += (size_t)EV*4;
  int* csr_eid = (int*)(w + off); off += (size_t)EV*4;
  int* rp      = (int*)(w + off); off += (size_t)(NBV+64)*4;
  int* dcnt    = (int*)(w + off); off += (size_t)(NBV+64)*4;
  int* bsum    = (int*)(w + off); off += 1024;
  size_t needed = off;

  float sentinel = (ws_size >= needed) ? 0.125f : 0.875f;
  k_sentinel<<<1, 128, 0, stream>>>(out, sentinel);

  const int* srcA = ei;
  const int* dstA = ei + EV;

  // ---- setup ----
  k_fill1<<<NBV/256, 256, 0, stream>>>(nmask, NBV);
  k_zero_i<<<(NBV+256)/256, 256, 0, stream>>>(dcnt, NBV+1);
  k_hist<<<EV/256, 256, 0, stream>>>(dstA, dcnt);
  k_scan1<<<256, 256, 0, stream>>>(dcnt, rp, bsum);
  k_scan2<<<1, 256, 0, stream>>>(bsum);
  k_scan3<<<256, 256, 0, stream>>>(rp, dcnt, bsum);
  k_zero_i<<<(NBV+256)/256, 256, 0, stream>>>(dcnt, NBV+1);
  k_scatter<<<EV/256, 256, 0, stream>>>(srcA, dstA, rp, dcnt, csr_src, csr_eid);
  k_ve<<<1, 32, 0, stream>>>(g_we, g_ae, sml+20);
  k_ale<<<EV/256, 256, 0, stream>>>(ea, sml+20, ALE);

  // ---- block 1: SAGE -> TopK(410) -> gap  (x -> F1) ----
  k_invnorm<<<1, 128, 0, stream>>>(p1_w, sml);
  k_sage_agg<<<(NBV*32)/256, 256, 0, stream>>>(x, nmask, rp, csr_src, AGG, 0);
  k_gemm<<<NBV/128, 512, 0, stream>>>(AGG, x, c1_wl, c1_wr, c1_bl, F1, 1, 1, 1);
  k_score1<<<(NBV*32)/256, 256, 0, stream>>>(F1, p1_w, sml, sA);
  k_pool<<<BV, 512, 0, stream>>>(sA, nmask, sel, K1V);
  k_scale_part<<<BV*8, 128, 0, stream>>>(F1, sel, gprt);
  k_gap_final<<<BV, 128, 0, stream>>>(gprt, x1g, 1.f/(float)K1V);

  // ---- block 2: SAGE -> SAGPool(205) -> gap  (F1 -> F2) ----
  k_sage_agg<<<(NBV*32)/256, 256, 0, stream>>>(F1, nmask, rp, csr_src, AGG, 1);
  k_gemm<<<NBV/128, 512, 0, stream>>>(AGG, F1, c2_wl, c2_wr, c2_bl, F2, 1, 1, 1);
  k_qr<<<(NBV*32)/256, 256, 0, stream>>>(F2, p2_wrel, p2_wroot, qv, rv);
  k_gconv<<<NBV/256, 256, 0, stream>>>(qv, rv, nmask, rp, csr_src, p2_brel, sA);
  k_pool<<<BV, 512, 0, stream>>>(sA, nmask, sel, K2V);
  k_scale_part<<<BV*8, 128, 0, stream>>>(F2, sel, gprt);
  k_gap_final<<<BV, 128, 0, stream>>>(gprt, x2g, 1.f/(float)K2V);

  // ---- block 3: GAT -> SAGPool(103) -> gap  (F2 -> xs=AGG -> F1) ----
  k_gemm<<<NBV/128, 512, 0, stream>>>(F2, F2, g_w, g_w, g_b, AGG, 0, 0, 0);  // xs = F2 @ g_w
  k_heads<<<(NBV*4)/256, 256, 0, stream>>>(AGG, g_as, g_ad, alS, alD);
  k_ea_part<<<256, 256, 0, stream>>>(ea, srcA, dstA, nmask, eprt);
  k_ea_final<<<1, 64, 0, stream>>>(eprt, sml+8);
  k_alse<<<1, 64, 0, stream>>>(sml+8, sml+20, sml+16);
  k_gat<<<(NBV*32)/256, 256, 0, stream>>>(AGG, alS, alD, ALE, nmask, rp, csr_src, csr_eid, sml+16, g_b, F1);
  k_qr<<<(NBV*32)/256, 256, 0, stream>>>(F1, p3_wrel, p3_wroot, qv, rv);
  k_gconv<<<NBV/256, 256, 0, stream>>>(qv, rv, nmask, rp, csr_src, p3_brel, sA);
  k_pool<<<BV, 512, 0, stream>>>(sA, nmask, sel, K3V);
  k_scale_part<<<BV*8, 128, 0, stream>>>(F1, sel, gprt);
  k_gap_final<<<BV, 128, 0, stream>>>(gprt, x3g, 1.f/(float)K3V);

  // ---- readout MLP ----
  k_mlp<<<BV, 128, 0, stream>>>(x1g, x2g, x3g, l1_w, l1_b, l2_w, l2_b, l3_w, l3_b, out);
}

// Round 5
// 673.957 us; speedup vs baseline: 5.9168x; 1.0180x over previous
//
#include <hip/hip_runtime.h>
#include <math.h>

#define NBV 65536
#define EV  1048576
#define BV  128
#define K1V 410
#define K2V 205
#define K3V 103
#define NL2 (BV*K2V)     // 26240 live nodes after pool2 (GEMM3/heads domain)
#define NEG_BIG (-1.0e38f)

__device__ __forceinline__ float lrelu(float x){ return x > 0.f ? x : 0.2f*x; }

// ---------------- diagnostics sentinel ----------------
__global__ void k_sentinel(float* out, float v){
  int i = threadIdx.x;
  if (i < 128) out[i] = v;
}

// ---------------- utility ----------------
__global__ void k_init1(float* nmask, int* dcnt){
  int i = blockIdx.x*blockDim.x + threadIdx.x;
  if (i < NBV) nmask[i] = 1.f;
  if (i < NBV+1) dcnt[i] = 0;
}

__global__ void k_zero_i(int* p, int n){
  int i = blockIdx.x*blockDim.x + threadIdx.x;
  if (i < n) p[i] = 0;
}

// ---------------- CSR build (int atomics only) ----------------
__global__ void k_hist(const int* dst, int* dcnt){
  int e = blockIdx.x*blockDim.x + threadIdx.x;
  if (e < EV) atomicAdd(&dcnt[dst[e]], 1);
}

__global__ void k_scan1(const int* dcnt, int* rp, int* bsum){
  __shared__ int sc[256];
  int t = threadIdx.x, i = blockIdx.x*256 + t;
  int v = dcnt[i];
  sc[t] = v; __syncthreads();
  for (int o = 1; o < 256; o <<= 1){
    int x = (t >= o) ? sc[t-o] : 0;
    __syncthreads();
    sc[t] += x;
    __syncthreads();
  }
  rp[i] = sc[t];
  if (t == 255) bsum[blockIdx.x] = sc[t];
}

__global__ void k_scan2(int* bsum){
  __shared__ int sc[256];
  int t = threadIdx.x;
  int v = bsum[t];
  sc[t] = v; __syncthreads();
  for (int o = 1; o < 256; o <<= 1){
    int x = (t >= o) ? sc[t-o] : 0;
    __syncthreads();
    sc[t] += x;
    __syncthreads();
  }
  bsum[t] = sc[t] - v;
}

__global__ void k_scan3(int* rp, const int* dcnt, const int* bsum){
  int t = threadIdx.x, i = blockIdx.x*256 + t;
  rp[i] = rp[i] - dcnt[i] + bsum[blockIdx.x];
  if (i == 0) rp[NBV] = EV;
}

__global__ void k_scatter(const int* src, const int* dst, const int* rp, int* fill,
                          int* csr_src, int* csr_eid){
  int e = blockIdx.x*blockDim.x + threadIdx.x;
  if (e < EV){
    int d = dst[e];
    int pos = atomicAdd(&fill[d], 1);
    int slot = rp[d] + pos;
    csr_src[slot] = src[e];
    csr_eid[slot] = e;
  }
}

// ---------------- small precomputes (merged: ve + invnorm, 1 launch) ----------------
__global__ void k_ve_inv(const float* g_we, const float* g_ae, const float* p1w, float* sml){
  __shared__ float sc[128];
  int t = threadIdx.x;
  if (t < 28){
    int ed = t >> 2, h = t & 3;
    float a = 0.f;
    for (int c = 0; c < 32; c++) a += g_we[ed*128 + h*32 + c] * g_ae[h*32 + c];
    sml[20 + t] = a;
  }
  float v = p1w[t];
  sc[t] = v*v; __syncthreads();
  for (int o = 64; o > 0; o >>= 1){ if (t < o) sc[t] += sc[t+o]; __syncthreads(); }
  if (t == 0) sml[0] = 1.f / sqrtf(sc[0]);
}

__global__ void k_ale(const float* ea, const float* ve, float* ALE){
  int e = blockIdx.x*blockDim.x + threadIdx.x;
  if (e < EV){
    float a0=0.f,a1=0.f,a2=0.f,a3=0.f;
    for (int ed = 0; ed < 7; ed++){
      float x = ea[e*7 + ed];
      a0 += x*ve[ed*4+0]; a1 += x*ve[ed*4+1]; a2 += x*ve[ed*4+2]; a3 += x*ve[ed*4+3];
    }
    float4 o; o.x=a0; o.y=a1; o.z=a2; o.w=a3;
    *(float4*)&ALE[(size_t)e*4] = o;
  }
}

// ---------------- SAGE mean aggregation (XCD-swizzled; mask-gated gathers) ----------------
// Loads moved UNDER the nmask check: nm is uniform across the 32-lane node group,
// so dead-src float4 gathers are exec-masked away (pure traffic cut, same math).
__global__ void __launch_bounds__(256) k_sage_agg(const float* X, const float* nmask,
    const int* rp, const int* csr_src, float* AGG, int masked){
  int g = blockIdx.x & 127;
  int blk = blockIdx.x >> 7;
  int i = g*512 + blk*8 + (threadIdx.x >> 5);
  int c4 = threadIdx.x & 31;
  float ax=0.f,ay=0.f,az=0.f,aw=0.f,cnt=0.f;
  if (!masked || nmask[i] > 0.f){
    int r0 = rp[i], r1 = rp[i+1];
    int s = r0;
    for (; s + 4 <= r1; s += 4){
      int sn0 = csr_src[s+0], sn1 = csr_src[s+1], sn2 = csr_src[s+2], sn3 = csr_src[s+3];
      float nm0 = masked ? nmask[sn0] : 1.f;
      float nm1 = masked ? nmask[sn1] : 1.f;
      float nm2 = masked ? nmask[sn2] : 1.f;
      float nm3 = masked ? nmask[sn3] : 1.f;
      if (nm0 > 0.f){ float4 v = *(const float4*)&X[((size_t)sn0 << 7) + (c4 << 2)];
                      ax += v.x; ay += v.y; az += v.z; aw += v.w; cnt += 1.f; }
      if (nm1 > 0.f){ float4 v = *(const float4*)&X[((size_t)sn1 << 7) + (c4 << 2)];
                      ax += v.x; ay += v.y; az += v.z; aw += v.w; cnt += 1.f; }
      if (nm2 > 0.f){ float4 v = *(const float4*)&X[((size_t)sn2 << 7) + (c4 << 2)];
                      ax += v.x; ay += v.y; az += v.z; aw += v.w; cnt += 1.f; }
      if (nm3 > 0.f){ float4 v = *(const float4*)&X[((size_t)sn3 << 7) + (c4 << 2)];
                      ax += v.x; ay += v.y; az += v.z; aw += v.w; cnt += 1.f; }
    }
    for (; s < r1; s++){
      int sn = csr_src[s];
      float nm = masked ? nmask[sn] : 1.f;
      if (nm > 0.f){
        const float4 v = *(const float4*)&X[((size_t)sn << 7) + (c4 << 2)];
        ax += v.x; ay += v.y; az += v.z; aw += v.w; cnt += 1.f;
      }
    }
  }
  float inv = 1.f / fmaxf(cnt, 1.f);
  float4 o; o.x = ax*inv; o.y = ay*inv; o.z = az*inv; o.w = aw*inv;
  *(float4*)&AGG[((size_t)i << 7) + (c4 << 2)] = o;
}

// ---------------- dual GEMM f32, W-resident, register-parked A pipeline ----------------
// PROVEN core: 66 us/dispatch, 64 VGPR, zero scratch (R0/R4 counters).
// LESSON (r13-r15): do NOT stream W in K-chunks with a 2-deep dbuf — true VGPR
// need >128, spills at ANY budget (measured 32/40/128-VGPR variants, 2.3-4.9GB
// scratch). And __launch_bounds__ arg2 here = CUDA-style min-BLOCKS-per-CU.
// NEW: (a) optional row-compaction via ridx (GEMM3 runs only live rows),
// (b) fused score/qr epilogue replicating k_score1/k_qr bit-exactly:
//     same per-lane float4 dot expression, same width-32 shfl_down tree
//     (lane colg holds cols 4c..4c+3 == k_score1's c4 layout).
__global__ void __launch_bounds__(512) k_gemm(const float* A1, const float* A2,
    const float* W1, const float* W2, const float* bias,
    float* OUT, int has2, int relu, int hasb,
    const int* ridx, int sc_mode,
    const float* sw1, const float* sw2, const float* sinv,
    float* so1, float* so2){
  __shared__ float ws[128][128];
  __shared__ float as[16][136];
  int t = threadIdx.x;
  int n0 = blockIdx.x * 128;
  int rowg = t >> 5;
  int colg = t & 31;
  int rb = rowg * 8;
  int jb = colg * 4;
  int an = t >> 2;              // A-stage row 0..127
  int ak = (t & 3) << 2;        // A-stage k offset {0,4,8,12}
  int arow = ridx ? ridx[n0 + an] : (n0 + an);
  float acc[8][4];
  for (int r = 0; r < 8; r++)
    for (int j = 0; j < 4; j++) acc[r][j] = 0.f;
  int nmat = has2 ? 2 : 1;
  for (int m = 0; m < nmat; m++){
    const float* A = (m == 0) ? A1 : A2;
    const float* W = (m == 0) ? W1 : W2;
    __syncthreads();   // prior readers of ws/as done (no-op cost at m==0)
    for (int ii = 0; ii < 8; ii++){
      int idx4 = t + 512*ii;
      int kk = idx4 >> 5;
      int jj = (idx4 & 31) << 2;
      *(float4*)&ws[kk][jj] = *(const float4*)&W[kk*128 + jj];
    }
    float4 rA = *(const float4*)&A[((size_t)arow << 7) + ak];   // chunk 0
    for (int c = 0; c < 8; c++){
      if (c > 0) __syncthreads();        // prior compute done reading as
      as[ak+0][an] = rA.x;
      as[ak+1][an] = rA.y;
      as[ak+2][an] = rA.z;
      as[ak+3][an] = rA.w;
      __syncthreads();                   // as (and ws on c==0) visible
      if (c+1 < 8)
        rA = *(const float4*)&A[((size_t)arow << 7) + (c+1)*16 + ak];  // prefetch
      int kb = c*16;
      for (int kk = 0; kk < 16; kk++){
        float4 wv = *(const float4*)&ws[kb+kk][jb];
        float4 aL = *(const float4*)&as[kk][rb];
        float4 aH = *(const float4*)&as[kk][rb+4];
        float a0=aL.x,a1=aL.y,a2=aL.z,a3=aL.w,a4=aH.x,a5=aH.y,a6=aH.z,a7=aH.w;
        acc[0][0]+=a0*wv.x; acc[0][1]+=a0*wv.y; acc[0][2]+=a0*wv.z; acc[0][3]+=a0*wv.w;
        acc[1][0]+=a1*wv.x; acc[1][1]+=a1*wv.y; acc[1][2]+=a1*wv.z; acc[1][3]+=a1*wv.w;
        acc[2][0]+=a2*wv.x; acc[2][1]+=a2*wv.y; acc[2][2]+=a2*wv.z; acc[2][3]+=a2*wv.w;
        acc[3][0]+=a3*wv.x; acc[3][1]+=a3*wv.y; acc[3][2]+=a3*wv.z; acc[3][3]+=a3*wv.w;
        acc[4][0]+=a4*wv.x; acc[4][1]+=a4*wv.y; acc[4][2]+=a4*wv.z; acc[4][3]+=a4*wv.w;
        acc[5][0]+=a5*wv.x; acc[5][1]+=a5*wv.y; acc[5][2]+=a5*wv.z; acc[5][3]+=a5*wv.w;
        acc[6][0]+=a6*wv.x; acc[6][1]+=a6*wv.y; acc[6][2]+=a6*wv.z; acc[6][3]+=a6*wv.w;
        acc[7][0]+=a7*wv.x; acc[7][1]+=a7*wv.y; acc[7][2]+=a7*wv.z; acc[7][3]+=a7*wv.w;
      }
    }
  }
  float bj0=0.f,bj1=0.f,bj2=0.f,bj3=0.f;
  if (hasb){
    bj0 = bias[jb+0]; bj1 = bias[jb+1]; bj2 = bias[jb+2]; bj3 = bias[jb+3];
  }
  int orow[8];
  for (int r = 0; r < 8; r++) orow[r] = ridx ? ridx[n0+rb+r] : (n0+rb+r);
  float w1x=0.f,w1y=0.f,w1z=0.f,w1w=0.f, w2x=0.f,w2y=0.f,w2z=0.f,w2w=0.f;
  if (sc_mode){
    float4 t1 = *(const float4*)&sw1[jb];
    w1x=t1.x; w1y=t1.y; w1z=t1.z; w1w=t1.w;
    if (sc_mode == 2){
      float4 t2 = *(const float4*)&sw2[jb];
      w2x=t2.x; w2y=t2.y; w2z=t2.z; w2w=t2.w;
    }
  }
  float pd1[8], pd2[8];
  for (int r = 0; r < 8; r++){
    float4 o;
    o.x = acc[r][0]+bj0; o.y = acc[r][1]+bj1; o.z = acc[r][2]+bj2; o.w = acc[r][3]+bj3;
    if (relu){
      o.x = fmaxf(o.x,0.f); o.y = fmaxf(o.y,0.f); o.z = fmaxf(o.z,0.f); o.w = fmaxf(o.w,0.f);
    }
    if (sc_mode){
      pd1[r] = o.x*w1x + o.y*w1y + o.z*w1z + o.w*w1w;
      if (sc_mode == 2) pd2[r] = o.x*w2x + o.y*w2y + o.z*w2z + o.w*w2w;
    }
    *(float4*)&OUT[((size_t)orow[r] << 7) + jb] = o;
  }
  if (sc_mode == 1){
    float inv = sinv[0];
    for (int r = 0; r < 8; r++){
      float a = pd1[r];
      for (int o = 16; o > 0; o >>= 1) a += __shfl_down(a, o, 32);
      if (colg == 0) so1[orow[r]] = tanhf(a * inv);
    }
  } else if (sc_mode == 2){
    for (int r = 0; r < 8; r++){
      float a = pd1[r];
      float b = pd2[r];
      for (int o = 16; o > 0; o >>= 1){
        a += __shfl_down(a, o, 32);
        b += __shfl_down(b, o, 32);
      }
      if (colg == 0){ so1[orow[r]] = a; so2[orow[r]] = b; }
    }
  }
}

__global__ void k_gconv(const float* q, const float* r, const float* nmask,
    const int* rp, const int* csr_src, const float* brel, float* s){
  int i = blockIdx.x*blockDim.x + threadIdx.x;
  if (i >= NBV) return;
  float acc = 0.f;
  if (nmask[i] > 0.f){
    int r0 = rp[i], r1 = rp[i+1];
    int t2 = r0;
    for (; t2 + 4 <= r1; t2 += 4){
      int sn0 = csr_src[t2+0], sn1 = csr_src[t2+1], sn2 = csr_src[t2+2], sn3 = csr_src[t2+3];
      float nm0 = nmask[sn0], nm1 = nmask[sn1], nm2 = nmask[sn2], nm3 = nmask[sn3];
      if (nm0 > 0.f) acc += q[sn0];
      if (nm1 > 0.f) acc += q[sn1];
      if (nm2 > 0.f) acc += q[sn2];
      if (nm3 > 0.f) acc += q[sn3];
    }
    for (; t2 < r1; t2++){
      int sn = csr_src[t2];
      if (nmask[sn] > 0.f) acc += q[sn];
    }
  }
  s[i] = tanhf(acc + brel[0] + r[i]);
}

// ---------------- top-k pool (stable tie-break == jax.lax.top_k) ----------------
// rank is a total order (unique 0..511 per graph); selected ranks are 0..K-1,
// so cidx[b*K + rank] = i is a race-free compaction list (used by GEMM3/heads).
__global__ void __launch_bounds__(512) k_pool(const float* s, float* nmask, float* sel,
                                              int K, int* cidx){
  __shared__ float sc[512];
  int b = blockIdx.x, t = threadIdx.x;
  int i = b*512 + t;
  float nm = nmask[i];
  float sv = s[i];
  float ms = (nm > 0.f) ? sv : NEG_BIG;
  sc[t] = ms;
  __syncthreads();
  int rank = 0;
  for (int j = 0; j < 512; j++){
    float o = sc[j];
    rank += ((o > ms) || (o == ms && j < t)) ? 1 : 0;
  }
  bool selb = rank < K;
  nmask[i] = selb ? 1.f : 0.f;
  sel[i] = selb ? sv : 0.f;
  if (cidx && selb) cidx[b*K + rank] = i;
}

// scale kept rows by score (in place) + gap partials — no atomics.
__global__ void __launch_bounds__(128) k_scale_part(float* X, const float* sel, float* part){
  int b = blockIdx.x >> 3, q = blockIdx.x & 7, c = threadIdx.x;
  float acc = 0.f;
  for (int n = q*64; n < q*64 + 64; n++){
    int i = b*512 + n;
    float v = X[((size_t)i << 7) + c] * sel[i];
    X[((size_t)i << 7) + c] = v;
    acc += v;
  }
  part[(size_t)blockIdx.x*128 + c] = acc;
}

__global__ void __launch_bounds__(128) k_gap_final(const float* part, float* gap, float invK){
  int b = blockIdx.x, c = threadIdx.x;
  float s = 0.f;
  for (int q = 0; q < 8; q++) s += part[(size_t)(b*8+q)*128 + c];
  gap[b*128 + c] = s * invK;
}

// ---------------- GAT pieces ----------------
// heads now runs only on live (compacted) nodes; dead alS/alD stay stale but
// are never read (all consumers nmask-gated).
__global__ void k_heads(const float* xs, const float* a_s, const float* a_d,
                        const int* cidx, int nlive4, float* alS, float* alD){
  int gid = blockIdx.x*blockDim.x + threadIdx.x;
  if (gid >= nlive4) return;
  int ii = gid >> 2, h = gid & 3;
  int i = cidx[ii];
  const float4* xr = (const float4*)&xs[((size_t)i << 7) + h*32];
  const float4* wa = (const float4*)&a_s[h*32];
  const float4* wd = (const float4*)&a_d[h*32];
  float as_ = 0.f, ad_ = 0.f;
  for (int c4 = 0; c4 < 8; c4++){
    float4 v = xr[c4]; float4 A = wa[c4]; float4 D = wd[c4];
    as_ += v.x*A.x + v.y*A.y + v.z*A.z + v.w*A.w;
    ad_ += v.x*D.x + v.y*D.y + v.z*D.z + v.w*D.w;
  }
  alS[i*4 + h] = as_; alD[i*4 + h] = ad_;
}

// edge-attr masked mean: per-block partials (no atomics)
__global__ void __launch_bounds__(256) k_ea_part(const float* ea, const int* srcA, const int* dstA,
    const float* nmask, float* part){
  float p[8] = {0.f,0.f,0.f,0.f,0.f,0.f,0.f,0.f};
  for (int e = blockIdx.x*256 + threadIdx.x; e < EV; e += 256*256){
    if (nmask[srcA[e]] > 0.f && nmask[dstA[e]] > 0.f){
      for (int d = 0; d < 7; d++) p[d] += ea[e*7 + d];
      p[7] += 1.f;
    }
  }
  __shared__ float red[256];
  for (int comp = 0; comp < 8; comp++){
    red[threadIdx.x] = p[comp]; __syncthreads();
    for (int o = 128; o > 0; o >>= 1){ if (threadIdx.x < o) red[threadIdx.x] += red[threadIdx.x + o]; __syncthreads(); }
    if (threadIdx.x == 0) part[blockIdx.x*8 + comp] = red[0];
    __syncthreads();
  }
}

__global__ void k_ea_final(const float* part, float* easum){
  int h = threadIdx.x;
  if (h < 8){
    float s = 0.f;
    for (int b = 0; b < 256; b++) s += part[b*8 + h];
    easum[h] = s;
  }
}

__global__ void k_alse(const float* easum, const float* ve, float* alse){
  if (threadIdx.x == 0 && blockIdx.x == 0){
    float cnt = fmaxf(easum[7], 1.f);
    for (int h = 0; h < 4; h++){
      float s = 0.f;
      for (int ed = 0; ed < 7; ed++) s += (easum[ed]/cnt) * ve[ed*4 + h];
      alse[h] = s;
    }
  }
}

// GAT: 32 threads/node, XCD-swizzled, mask-gated gathers + in-order online softmax.
// Epilogue fuses k_qr (p3) bit-exactly: lane==cidx holds cols 4*lane..4*lane+3,
// same dot expression + width-32 shfl tree as the standalone kernel had.
__global__ void __launch_bounds__(256) k_gat(const float* xs, const float* alS, const float* alD,
    const float* ALE, const float* nmask, const int* rp, const int* csr_src,
    const int* csr_eid, const float* alse, const float* g_b,
    const float* wrel, const float* wroot, float* qv, float* rv, float* OUT){
  int g = blockIdx.x & 127;
  int blk = blockIdx.x >> 7;
  int i = g*512 + blk*8 + (threadIdx.x >> 5);
  int lane = threadIdx.x & 31;
  int h = lane >> 3;
  int cidx = h*8 + (lane & 7);   // == lane
  float nmi = nmask[i];
  const float4* xs4 = (const float4*)xs;
  float m = 0.f, den = 0.f;
  float4 acc; acc.x=0.f; acc.y=0.f; acc.z=0.f; acc.w=0.f;
  if (nmi > 0.f){
    float ald_i = alD[i*4 + h];
    m = lrelu(alS[i*4 + h] + ald_i + alse[h]);   // aself
    den = 1.f;
    acc = xs4[(size_t)i*32 + cidx];
    int r0 = rp[i], r1 = rp[i+1];
    int s = r0;
    for (; s + 4 <= r1; s += 4){
      int sn0 = csr_src[s+0], sn1 = csr_src[s+1], sn2 = csr_src[s+2], sn3 = csr_src[s+3];
      float nm0 = nmask[sn0], nm1 = nmask[sn1], nm2 = nmask[sn2], nm3 = nmask[sn3];
      if (nm0 > 0.f){
        float a = lrelu(alS[sn0*4 + h] + ald_i + ALE[(size_t)csr_eid[s+0]*4 + h]);
        float4 v = xs4[(size_t)sn0*32 + cidx];
        float mn = fmaxf(m, a); float pm = expf(m - mn); float pa = expf(a - mn);
        den = den*pm + pa;
        acc.x = acc.x*pm + pa*v.x; acc.y = acc.y*pm + pa*v.y;
        acc.z = acc.z*pm + pa*v.z; acc.w = acc.w*pm + pa*v.w;
        m = mn;
      }
      if (nm1 > 0.f){
        float a = lrelu(alS[sn1*4 + h] + ald_i + ALE[(size_t)csr_eid[s+1]*4 + h]);
        float4 v = xs4[(size_t)sn1*32 + cidx];
        float mn = fmaxf(m, a); float pm = expf(m - mn); float pa = expf(a - mn);
        den = den*pm + pa;
        acc.x = acc.x*pm + pa*v.x; acc.y = acc.y*pm + pa*v.y;
        acc.z = acc.z*pm + pa*v.z; acc.w = acc.w*pm + pa*v.w;
        m = mn;
      }
      if (nm2 > 0.f){
        float a = lrelu(alS[sn2*4 + h] + ald_i + ALE[(size_t)csr_eid[s+2]*4 + h]);
        float4 v = xs4[(size_t)sn2*32 + cidx];
        float mn = fmaxf(m, a); float pm = expf(m - mn); float pa = expf(a - mn);
        den = den*pm + pa;
        acc.x = acc.x*pm + pa*v.x; acc.y = acc.y*pm + pa*v.y;
        acc.z = acc.z*pm + pa*v.z; acc.w = acc.w*pm + pa*v.w;
        m = mn;
      }
      if (nm3 > 0.f){
        float a = lrelu(alS[sn3*4 + h] + ald_i + ALE[(size_t)csr_eid[s+3]*4 + h]);
        float4 v = xs4[(size_t)sn3*32 + cidx];
        float mn = fmaxf(m, a); float pm = expf(m - mn); float pa = expf(a - mn);
        den = den*pm + pa;
        acc.x = acc.x*pm + pa*v.x; acc.y = acc.y*pm + pa*v.y;
        acc.z = acc.z*pm + pa*v.z; acc.w = acc.w*pm + pa*v.w;
        m = mn;
      }
    }
    for (; s < r1; s++){
      int sn = csr_src[s];
      if (nmask[sn] > 0.f){
        float a = lrelu(alS[sn*4 + h] + ald_i + ALE[(size_t)csr_eid[s]*4 + h]);
        float4 v = xs4[(size_t)sn*32 + cidx];
        float mn = fmaxf(m, a); float pm = expf(m - mn); float pa = expf(a - mn);
        den = den*pm + pa;
        acc.x = acc.x*pm + pa*v.x; acc.y = acc.y*pm + pa*v.y;
        acc.z = acc.z*pm + pa*v.z; acc.w = acc.w*pm + pa*v.w;
        m = mn;
      }
    }
  }
  den = fmaxf(den, 1e-16f);
  float rd = 1.f/den;
  int cb = cidx << 2;
  float4 o;
  o.x = fmaxf(acc.x*rd + g_b[cb+0], 0.f);
  o.y = fmaxf(acc.y*rd + g_b[cb+1], 0.f);
  o.z = fmaxf(acc.z*rd + g_b[cb+2], 0.f);
  o.w = fmaxf(acc.w*rd + g_b[cb+3], 0.f);
  *(float4*)&OUT[((size_t)i << 7) + cb] = o;
  // fused k_qr (p3): identical per-lane dot + width-32 tree as standalone k_qr
  float4 wa = *(const float4*)&wrel[cb];
  float4 wb = *(const float4*)&wroot[cb];
  float aq = o.x*wa.x + o.y*wa.y + o.z*wa.z + o.w*wa.w;
  float ar = o.x*wb.x + o.y*wb.y + o.z*wb.z + o.w*wb.w;
  for (int off = 16; off > 0; off >>= 1){
    aq += __shfl_down(aq, off, 32);
    ar += __shfl_down(ar, off, 32);
  }
  if (lane == 0){ qv[i] = aq; rv[i] = ar; }
}

// ---------------- final MLP ----------------
__global__ void __launch_bounds__(128) k_mlp(const float* x1g, const float* x2g, const float* x3g,
    const float* l1w, const float* l1b, const float* l2w, const float* l2b,
    const float* l3w, const float* l3b, float* out){
  __shared__ float hh[128];
  __shared__ float h2[128];
  __shared__ float h3[64];
  int b = blockIdx.x, t = threadIdx.x;
  hh[t] = x1g[b*128 + t] + x2g[b*128 + t] + x3g[b*128 + t];
  __syncthreads();
  float a = l1b[t];
  for (int k = 0; k < 128; k++) a += hh[k] * l1w[k*128 + t];
  h2[t] = fmaxf(a, 0.f);
  __syncthreads();
  if (t < 64){
    float a2 = l2b[t];
    for (int k = 0; k < 128; k++) a2 += h2[k] * l2w[k*64 + t];
    h3[t] = fmaxf(a2, 0.f);
  }
  __syncthreads();
  if (t == 0){
    float z = l3b[0];
    for (int k = 0; k < 64; k++) z += h3[k] * l3w[k];
    out[b] = 1.f/(1.f + expf(-z));
  }
}

// ---------------- launch ----------------
extern "C" void kernel_launch(void* const* d_in, const int* in_sizes, int n_in,
                              void* d_out, int out_size, void* d_ws, size_t ws_size,
                              hipStream_t stream){
  const float* x       = (const float*)d_in[0];
  const int*   ei      = (const int*)d_in[1];
  const float* ea      = (const float*)d_in[2];
  const float* c1_wl   = (const float*)d_in[3];
  const float* c1_bl   = (const float*)d_in[4];
  const float* c1_wr   = (const float*)d_in[5];
  const float* p1_w    = (const float*)d_in[6];
  const float* c2_wl   = (const float*)d_in[7];
  const float* c2_bl   = (const float*)d_in[8];
  const float* c2_wr   = (const float*)d_in[9];
  const float* p2_wrel = (const float*)d_in[10];
  const float* p2_brel = (const float*)d_in[11];
  const float* p2_wroot= (const float*)d_in[12];
  const float* g_w     = (const float*)d_in[13];
  const float* g_as    = (const float*)d_in[14];
  const float* g_ad    = (const float*)d_in[15];
  const float* g_we    = (const float*)d_in[16];
  const float* g_ae    = (const float*)d_in[17];
  const float* g_b     = (const float*)d_in[18];
  const float* p3_wrel = (const float*)d_in[19];
  const float* p3_brel = (const float*)d_in[20];
  const float* p3_wroot= (const float*)d_in[21];
  const float* l1_w    = (const float*)d_in[22];
  const float* l1_b    = (const float*)d_in[23];
  const float* l2_w    = (const float*)d_in[24];
  const float* l2_b    = (const float*)d_in[25];
  const float* l3_w    = (const float*)d_in[26];
  const float* l3_b    = (const float*)d_in[27];
  float* out = (float*)d_out;
  (void)in_sizes; (void)n_in; (void)out_size;

  // Workspace layout (f32, ~137 MB)
  char* w = (char*)d_ws;
  size_t off = 0;
  float* AGG  = (float*)(w + off); off += (size_t)NBV*128*4;
  float* F1   = (float*)(w + off); off += (size_t)NBV*128*4;
  float* F2   = (float*)(w + off); off += (size_t)NBV*128*4;
  float* ALE  = (float*)(w + off); off += (size_t)EV*4*4;
  float* sA   = (float*)(w + off); off += (size_t)NBV*4;
  float* sel  = (float*)(w + off); off += (size_t)NBV*4;
  float* qv   = (float*)(w + off); off += (size_t)NBV*4;
  float* rv   = (float*)(w + off); off += (size_t)NBV*4;
  float* nmask= (float*)(w + off); off += (size_t)NBV*4;
  float* alS  = (float*)(w + off); off += (size_t)NBV*4*4;
  float* alD  = (float*)(w + off); off += (size_t)NBV*4*4;
  float* x1g  = (float*)(w + off); off += (size_t)BV*128*4;
  float* x2g  = (float*)(w + off); off += (size_t)BV*128*4;
  float* x3g  = (float*)(w + off); off += (size_t)BV*128*4;
  float* sml  = (float*)(w + off); off += 64*4;      // [0]=invnorm [8..15]=easum [16..19]=alse [20..47]=ve
  float* eprt = (float*)(w + off); off += 2048*4;
  float* gprt = (float*)(w + off); off += (size_t)1024*128*4;
  int* csr_src = (int*)(w + off); off += (size_t)EV*4;
  int* csr_eid = (int*)(w + off); off += (size_t)EV*4;
  int* rp      = (int*)(w + off); off += (size_t)(NBV+64)*4;
  int* dcnt    = (int*)(w + off); off += (size_t)(NBV+64)*4;
  int* cidx    = (int*)(w + off); off += (size_t)NBV*4;
  int* bsum    = (int*)(w + off); off += 1024;
  size_t needed = off;

  float sentinel = (ws_size >= needed) ? 0.125f : 0.875f;
  k_sentinel<<<1, 128, 0, stream>>>(out, sentinel);

  const int* srcA = ei;
  const int* dstA = ei + EV;

  // ---- setup ----
  k_init1<<<(NBV+256)/256, 256, 0, stream>>>(nmask, dcnt);
  k_hist<<<EV/256, 256, 0, stream>>>(dstA, dcnt);
  k_scan1<<<256, 256, 0, stream>>>(dcnt, rp, bsum);
  k_scan2<<<1, 256, 0, stream>>>(bsum);
  k_scan3<<<256, 256, 0, stream>>>(rp, dcnt, bsum);
  k_zero_i<<<(NBV+256)/256, 256, 0, stream>>>(dcnt, NBV+1);
  k_scatter<<<EV/256, 256, 0, stream>>>(srcA, dstA, rp, dcnt, csr_src, csr_eid);
  k_ve_inv<<<1, 128, 0, stream>>>(g_we, g_ae, p1_w, sml);
  k_ale<<<EV/256, 256, 0, stream>>>(ea, sml+20, ALE);

  // ---- block 1: SAGE -> TopK(410) -> gap  (x -> F1; score fused in GEMM) ----
  k_sage_agg<<<(NBV*32)/256, 256, 0, stream>>>(x, nmask, rp, csr_src, AGG, 0);
  k_gemm<<<NBV/128, 512, 0, stream>>>(AGG, x, c1_wl, c1_wr, c1_bl, F1, 1, 1, 1,
                                      (const int*)nullptr, 1, p1_w, (const float*)nullptr, sml, sA, (float*)nullptr);
  k_pool<<<BV, 512, 0, stream>>>(sA, nmask, sel, K1V, (int*)nullptr);
  k_scale_part<<<BV*8, 128, 0, stream>>>(F1, sel, gprt);
  k_gap_final<<<BV, 128, 0, stream>>>(gprt, x1g, 1.f/(float)K1V);

  // ---- block 2: SAGE -> SAGPool(205) -> gap  (F1 -> F2; qr fused in GEMM) ----
  k_sage_agg<<<(NBV*32)/256, 256, 0, stream>>>(F1, nmask, rp, csr_src, AGG, 1);
  k_gemm<<<NBV/128, 512, 0, stream>>>(AGG, F1, c2_wl, c2_wr, c2_bl, F2, 1, 1, 1,
                                      (const int*)nullptr, 2, p2_wrel, p2_wroot, (const float*)nullptr, qv, rv);
  k_gconv<<<NBV/256, 256, 0, stream>>>(qv, rv, nmask, rp, csr_src, p2_brel, sA);
  k_pool<<<BV, 512, 0, stream>>>(sA, nmask, sel, K2V, cidx);
  k_scale_part<<<BV*8, 128, 0, stream>>>(F2, sel, gprt);
  k_gap_final<<<BV, 128, 0, stream>>>(gprt, x2g, 1.f/(float)K2V);

  // ---- block 3: GAT -> SAGPool(103) -> gap  (F2 -> xs=AGG -> F1) ----
  // GEMM3 compacted to the 26240 live rows (dead xs rows = stale-but-finite
  // AGG content, never read: heads compacted, gat gathers nmask-gated).
  k_gemm<<<NL2/128, 512, 0, stream>>>(F2, F2, g_w, g_w, g_b, AGG, 0, 0, 0,
                                      cidx, 0, (const float*)nullptr, (const float*)nullptr,
                                      (const float*)nullptr, (float*)nullptr, (float*)nullptr);
  k_heads<<<(NL2*4 + 255)/256, 256, 0, stream>>>(AGG, g_as, g_ad, cidx, NL2*4, alS, alD);
  k_ea_part<<<256, 256, 0, stream>>>(ea, srcA, dstA, nmask, eprt);
  k_ea_final<<<1, 64, 0, stream>>>(eprt, sml+8);
  k_alse<<<1, 64, 0, stream>>>(sml+8, sml+20, sml+16);
  k_gat<<<(NBV*32)/256, 256, 0, stream>>>(AGG, alS, alD, ALE, nmask, rp, csr_src, csr_eid,
                                          sml+16, g_b, p3_wrel, p3_wroot, qv, rv, F1);
  k_gconv<<<NBV/256, 256, 0, stream>>>(qv, rv, nmask, rp, csr_src, p3_brel, sA);
  k_pool<<<BV, 512, 0, stream>>>(sA, nmask, sel, K3V, (int*)nullptr);
  k_scale_part<<<BV*8, 128, 0, stream>>>(F1, sel, gprt);
  k_gap_final<<<BV, 128, 0, stream>>>(gprt, x3g, 1.f/(float)K3V);

  // ---- readout MLP ----
  k_mlp<<<BV, 128, 0, stream>>>(x1g, x2g, x3g, l1_w, l1_b, l2_w, l2_b, l3_w, l3_b, out);
}